// Round 4
// baseline (850.867 us; speedup 1.0000x reference)
//
#include <hip/hip_runtime.h>
#include <cstdint>
#include <cstddef>

#define NN 50000
#define NE 800000
#define NEPAD (NE + 3 * NN)  // CSR rows padded to multiple of 4
#define HID 128
#define NGRAPH 64
#define NCLASS 10
#define LHID 3
#define NSLICE 8   // feature slices of 16, one per XCD

// row-blocks of 16 rows: 50000/16 = 3125 exact; GEMM grid covers 391*8 = 3128
#define ROWBLK 3125
#define ROWBLK_PAD 3128
#define GEMM_GRID 391

// 1/sqrt(1+1e-5), computed in double, rounded to f32
static constexpr float BN_INV = 0.9999950000374996f;

typedef __attribute__((ext_vector_type(8))) __bf16 bf16x8;
typedef __attribute__((ext_vector_type(4))) float floatx4;
typedef __attribute__((ext_vector_type(4))) int intx4;

// ---------------- bf16 split helpers ----------------

__device__ __forceinline__ unsigned short f32_to_bf16_rne(float f) {
    unsigned int u = __float_as_uint(f);
    unsigned int r = (u + 0x7FFFu + ((u >> 16) & 1u)) >> 16;
    return (unsigned short)r;
}
__device__ __forceinline__ float bf16_to_f32(unsigned short h) {
    return __uint_as_float(((unsigned int)h) << 16);
}

__device__ __forceinline__ void gl2lds16(const void* g, void* l) {
    __builtin_amdgcn_global_load_lds((__attribute__((address_space(1))) void*)g,
                                     (__attribute__((address_space(3))) void*)l,
                                     16, 0, 0);
}

// ---------------- graph build ----------------

__global__ void k_deg(const int* __restrict__ ei, int* __restrict__ deg) {
    int e = blockIdx.x * 256 + threadIdx.x;
    if (e < NE) atomicAdd(&deg[ei[NE + e]], 1);
}

__global__ void k_dinv(const int* __restrict__ deg, float* __restrict__ dinv) {
    int i = blockIdx.x * 256 + threadIdx.x;
    if (i < NN) dinv[i] = rsqrtf((float)(deg[i] + 1));  // +1 self-loop
}

// scans over padded degree deg4 = (deg+3)&~3 so every CSR row start is 16B-aligned

__global__ void k_scan1(const int* __restrict__ deg, int* __restrict__ bsum) {
    __shared__ int s[256];
    int i = blockIdx.x * 256 + threadIdx.x;
    s[threadIdx.x] = (i < NN) ? ((deg[i] + 3) & ~3) : 0;
    __syncthreads();
    for (int o = 128; o > 0; o >>= 1) {
        if (threadIdx.x < o) s[threadIdx.x] += s[threadIdx.x + o];
        __syncthreads();
    }
    if (threadIdx.x == 0) bsum[blockIdx.x] = s[0];
}

__global__ void k_scan2(int* __restrict__ bsum, int nb) {
    if (threadIdx.x == 0 && blockIdx.x == 0) {
        int run = 0;
        for (int b = 0; b < nb; ++b) { int v = bsum[b]; bsum[b] = run; run += v; }
    }
}

__global__ void k_scan3(const int* __restrict__ deg, const int* __restrict__ bsum,
                        int* __restrict__ rowptr) {
    __shared__ int s[256];
    int i = blockIdx.x * 256 + threadIdx.x;
    int v = (i < NN) ? ((deg[i] + 3) & ~3) : 0;
    s[threadIdx.x] = v;
    __syncthreads();
    for (int o = 1; o < 256; o <<= 1) {
        int tv = (threadIdx.x >= o) ? s[threadIdx.x - o] : 0;
        __syncthreads();
        s[threadIdx.x] += tv;
        __syncthreads();
    }
    if (i < NN) rowptr[i] = bsum[blockIdx.x] + s[threadIdx.x] - v;  // exclusive
}

__global__ void k_fill(const int* __restrict__ ei, const int* __restrict__ rowptr,
                       int* __restrict__ cursor, const float* __restrict__ dinv,
                       int* __restrict__ col, float* __restrict__ cfv) {
    int e = blockIdx.x * 256 + threadIdx.x;
    if (e >= NE) return;
    int s = ei[e];
    int d = ei[NE + e];
    int p = rowptr[d] + atomicAdd(&cursor[d], 1);
    col[p] = s;
    cfv[p] = dinv[s];
}

// ---------------- converters: fp32 -> swizzled bf16 hi/lo ----------------

__global__ void k_convA(const float* __restrict__ src, unsigned short* __restrict__ hi,
                        unsigned short* __restrict__ lo) {
    int u = blockIdx.x * 256 + threadIdx.x;  // 0 .. 800000-1 (one 16B output unit each)
    int lane = u & 63;
    int blk = u >> 6;
    int kblk = blk & 3;
    int rowBlock = blk >> 2;
    int m = rowBlock * 16 + (lane & 15);
    int k = kblk * 32 + (lane >> 4) * 8;
    const float4* p = (const float4*)&src[(size_t)m * 128 + k];
    float4 v0 = p[0];
    float4 v1 = p[1];
    float vals[8] = {v0.x, v0.y, v0.z, v0.w, v1.x, v1.y, v1.z, v1.w};
    union { unsigned short s[8]; uint4 v; } H, L;
#pragma unroll
    for (int j = 0; j < 8; ++j) {
        unsigned short h = f32_to_bf16_rne(vals[j]);
        H.s[j] = h;
        L.s[j] = f32_to_bf16_rne(vals[j] - bf16_to_f32(h));
    }
    *(uint4*)&hi[(size_t)u * 8] = H.v;
    *(uint4*)&lo[(size_t)u * 8] = L.v;
}

__global__ void k_convB(const float* __restrict__ W0, const float* __restrict__ Wh,
                        const float* __restrict__ Rh, unsigned short* __restrict__ hi,
                        unsigned short* __restrict__ lo) {
    int mat = blockIdx.y;
    const float* src = (mat == 0) ? W0
                     : (mat <= 3) ? (Wh + (size_t)(mat - 1) * 16384)
                                  : (Rh + (size_t)(mat - 4) * 16384);
    int u = blockIdx.x * 256 + threadIdx.x;  // 0..2047
    int lane = u & 63;
    int blk = u >> 6;
    int kblk = blk & 3;
    int nb = blk >> 2;
    int n = nb * 16 + (lane & 15);
    int k = kblk * 32 + (lane >> 4) * 8;
    union { unsigned short s[8]; uint4 v; } H, L;
#pragma unroll
    for (int j = 0; j < 8; ++j) {
        float f = src[(size_t)(k + j) * 128 + n];
        unsigned short h = f32_to_bf16_rne(f);
        H.s[j] = h;
        L.s[j] = f32_to_bf16_rne(f - bf16_to_f32(h));
    }
    size_t base = (size_t)mat * 16384 + (size_t)u * 8;
    *(uint4*)&hi[base] = H.v;
    *(uint4*)&lo[base] = L.v;
}

// ---------------- MFMA GEMM: C = A @ B, split-bf16 3-product ----------------
// Output written SLICE-MAJOR: C[((col>>4)*NN + row)*16 + (col&15)] so that the
// sliced SpMM's per-XCD working set (one 16-feature slice) is 3.2 MB (fits L2).

__global__ __launch_bounds__(256, 2) void k_gemm_mfma(
    const unsigned short* __restrict__ Ahi, const unsigned short* __restrict__ Alo,
    const unsigned short* __restrict__ Bhi, const unsigned short* __restrict__ Blo,
    float* __restrict__ C) {
    __shared__ unsigned short lds[4 * 8192];  // 64 KB
    unsigned short* AhiS = lds;
    unsigned short* AloS = lds + 8192;
    unsigned short* BhiS = lds + 16384;
    unsigned short* BloS = lds + 24576;

    const int tid = threadIdx.x;
    const int wave = tid >> 6;
    const int lane = tid & 63;
    const int wm = wave & 1;
    const int wn = wave >> 1;
    const int rb0 = blockIdx.x * 8;

    floatx4 acc[4][4];
    floatx4 zero = {0.f, 0.f, 0.f, 0.f};
#pragma unroll
    for (int i = 0; i < 4; ++i)
#pragma unroll
        for (int j = 0; j < 4; ++j) acc[i][j] = zero;

    for (int kc = 0; kc < 2; ++kc) {
#pragma unroll
        for (int it = 0; it < 4; ++it) {
            int b = it * 4 + wave;        // 0..15 : rb = b>>1, kb = b&1
            int rb = b >> 1;
            int kb = b & 1;
            size_t aOff = ((size_t)(rb0 + rb) * 4 + kc * 2 + kb) * 512 + (size_t)lane * 8;
            size_t bOff = ((size_t)rb * 4 + kc * 2 + kb) * 512 + (size_t)lane * 8;
            int ldsOff = b * 512;  // wave-uniform base; HW adds lane*16B
            gl2lds16(Ahi + aOff, AhiS + ldsOff);
            gl2lds16(Alo + aOff, AloS + ldsOff);
            gl2lds16(Bhi + bOff, BhiS + ldsOff);
            gl2lds16(Blo + bOff, BloS + ldsOff);
        }
        __syncthreads();

#pragma unroll
        for (int kb = 0; kb < 2; ++kb) {
            bf16x8 aH[4], aL[4], bH[4], bL[4];
#pragma unroll
            for (int t = 0; t < 4; ++t) {
                aH[t] = *(const bf16x8*)(AhiS + ((wm * 4 + t) * 2 + kb) * 512 + lane * 8);
                bH[t] = *(const bf16x8*)(BhiS + ((wn * 4 + t) * 2 + kb) * 512 + lane * 8);
            }
#pragma unroll
            for (int tm = 0; tm < 4; ++tm)
#pragma unroll
                for (int tn = 0; tn < 4; ++tn)
                    acc[tm][tn] = __builtin_amdgcn_mfma_f32_16x16x32_bf16(
                        aH[tm], bH[tn], acc[tm][tn], 0, 0, 0);
#pragma unroll
            for (int t = 0; t < 4; ++t)
                bL[t] = *(const bf16x8*)(BloS + ((wn * 4 + t) * 2 + kb) * 512 + lane * 8);
#pragma unroll
            for (int tm = 0; tm < 4; ++tm)
#pragma unroll
                for (int tn = 0; tn < 4; ++tn)
                    acc[tm][tn] = __builtin_amdgcn_mfma_f32_16x16x32_bf16(
                        aH[tm], bL[tn], acc[tm][tn], 0, 0, 0);
#pragma unroll
            for (int t = 0; t < 4; ++t)
                aL[t] = *(const bf16x8*)(AloS + ((wm * 4 + t) * 2 + kb) * 512 + lane * 8);
#pragma unroll
            for (int tm = 0; tm < 4; ++tm)
#pragma unroll
                for (int tn = 0; tn < 4; ++tn)
                    acc[tm][tn] = __builtin_amdgcn_mfma_f32_16x16x32_bf16(
                        aL[tm], bH[tn], acc[tm][tn], 0, 0, 0);
        }
        __syncthreads();
    }

    // epilogue: C/D layout col = lane&15, row = (lane>>4)*4 + r; slice-major store
    const int quad = lane >> 4;
    const int col0 = lane & 15;
    const int rowBase = rb0 * 16 + wm * 64;
#pragma unroll
    for (int tm = 0; tm < 4; ++tm) {
#pragma unroll
        for (int tn = 0; tn < 4; ++tn) {
            int sl = wn * 4 + tn;  // feature slice = col >> 4
#pragma unroll
            for (int r = 0; r < 4; ++r) {
                int row = rowBase + tm * 16 + quad * 4 + r;
                if (row < NN)
                    C[((size_t)sl * NN + row) * 16 + col0] = acc[tm][tn][r];
            }
        }
    }
}

// ---------------- sliced SpMM + epilogue (bias [+res] + BN + ReLU) ----------
// slice = blockIdx % 8 (XCD-affine under round-robin dispatch). Wave = 4 nodes
// x 16 features; per edge a 16-lane sub-group gathers a contiguous 64 B chunk
// from the 3.2 MB slice (L2-resident). Metadata via non-temporal loads.

template <bool RES>
__global__ __launch_bounds__(256) void k_spmm(const float* __restrict__ tS,
                                              const float* __restrict__ rS,
                                              const int* __restrict__ rowptr,
                                              const int* __restrict__ deg,
                                              const int* __restrict__ col,
                                              const float* __restrict__ cfv,
                                              const float* __restrict__ dinv,
                                              const float* __restrict__ bias,
                                              const float* __restrict__ gamma,
                                              const float* __restrict__ beta,
                                              float* __restrict__ hout) {
    const int s = blockIdx.x & 7;
    const int grp = blockIdx.x >> 3;      // 0..3124
    const int wave = threadIdx.x >> 6;
    const int lane = threadIdx.x & 63;
    const int ng = lane >> 4;
    const int fp = lane & 15;
    const int node = grp * 16 + wave * 4 + ng;  // < 50000 exactly

    const float* __restrict__ ts = tS + (size_t)s * NN * 16;
    const int start = rowptr[node];       // multiple of 4 -> 16B-aligned metadata
    const int cnt4 = (deg[node] + 3) >> 2;
    float ax = 0.f;
#pragma unroll 2
    for (int q = 0; q < cnt4; ++q) {
        intx4 cs = __builtin_nontemporal_load((const intx4*)&col[start + q * 4]);
        floatx4 wv = __builtin_nontemporal_load((const floatx4*)&cfv[start + q * 4]);
        float v0 = ts[cs.x * 16 + fp];
        float v1 = ts[cs.y * 16 + fp];
        float v2 = ts[cs.z * 16 + fp];
        float v3 = ts[cs.w * 16 + fp];
        ax = fmaf(wv.x, v0, ax);
        ax = fmaf(wv.y, v1, ax);
        ax = fmaf(wv.z, v2, ax);
        ax = fmaf(wv.w, v3, ax);
    }
    const float di = dinv[node];
    const int f = s * 16 + fp;
    const float tv = ts[node * 16 + fp];
    float cx = di * ax + di * di * tv + bias[f];
    if (RES) cx += rS[((size_t)s * NN + node) * 16 + fp];
    float ox = fmaxf(cx * (BN_INV * gamma[f]) + beta[f], 0.f);
    __builtin_nontemporal_store(ox, &hout[(size_t)node * 128 + f]);
}

// ---------------- pooling (segment max over sorted batch) ----------------

__device__ inline int lbound(const int* __restrict__ b, int v) {
    int lo = 0, hi = NN;
    while (lo < hi) {
        int mid = (lo + hi) >> 1;
        if (b[mid] < v) lo = mid + 1; else hi = mid;
    }
    return lo;
}

__global__ void k_pool(const float* __restrict__ h, const int* __restrict__ batch,
                       float* __restrict__ pooled) {
    __shared__ int sLo, sHi;
    int g = blockIdx.x >> 2;
    int ch = blockIdx.x & 3;
    if (threadIdx.x == 0) {
        sLo = lbound(batch, g);
        sHi = lbound(batch, g + 1);
    }
    __syncthreads();
    int lo = sLo, hi = sHi;
    int len = hi - lo;
    int per = (len + 3) >> 2;
    int s = lo + ch * per;
    int e = min(s + per, hi);
    float m = 0.0f;  // h >= 0 post-ReLU
    for (int i = s; i < e; ++i) m = fmaxf(m, h[(size_t)i * 128 + threadIdx.x]);
    if (s < e) atomicMax((unsigned int*)&pooled[g * 128 + threadIdx.x], __float_as_uint(m));
}

// ---------------- MLP head ----------------

__global__ void k_head(const float* __restrict__ pooled, const float* __restrict__ mW1,
                       const float* __restrict__ mb1, const float* __restrict__ mW2,
                       const float* __restrict__ mb2, float* __restrict__ out) {
    __shared__ float p[128];
    __shared__ float z[128];
    int g = blockIdx.x;
    int j = threadIdx.x;  // 128 threads
    p[j] = pooled[g * 128 + j];
    __syncthreads();
    float a = mb1[j];
#pragma unroll 8
    for (int k = 0; k < 128; ++k) a += p[k] * mW1[k * 128 + j];
    z[j] = fmaxf(a, 0.f);
    __syncthreads();
    if (j < NCLASS) {
        float o = mb2[j];
#pragma unroll 8
        for (int k = 0; k < 128; ++k) o += z[k] * mW2[k * NCLASS + j];
        out[g * NCLASS + j] = o;
    }
}

// ---------------- launcher ----------------

extern "C" void kernel_launch(void* const* d_in, const int* in_sizes, int n_in,
                              void* d_out, int out_size, void* d_ws, size_t ws_size,
                              hipStream_t stream) {
    const float* x   = (const float*)d_in[0];
    const int*   ei  = (const int*)d_in[1];
    const int* batch = (const int*)d_in[2];
    const float* W0  = (const float*)d_in[3];
    const float* b0  = (const float*)d_in[4];
    const float* g0  = (const float*)d_in[5];
    const float* be0 = (const float*)d_in[6];
    const float* Wh  = (const float*)d_in[7];
    const float* bh  = (const float*)d_in[8];
    const float* gh  = (const float*)d_in[9];
    const float* beh = (const float*)d_in[10];
    const float* Rh  = (const float*)d_in[11];
    const float* mW1 = (const float*)d_in[12];
    const float* mb1 = (const float*)d_in[13];
    const float* mW2 = (const float*)d_in[14];
    const float* mb2 = (const float*)d_in[15];
    float* out = (float*)d_out;

    char* ws = (char*)d_ws;
    size_t off = 0;
    auto alloc = [&](size_t bytes) -> void* {
        void* p = ws + off;
        off += (bytes + 255) & ~(size_t)255;
        return p;
    };
    int*   deg    = (int*)alloc((size_t)NN * 4);
    int*   rowptr = (int*)alloc((size_t)NN * 4);
    int*   cursor = (int*)alloc((size_t)NN * 4);
    float* dinv   = (float*)alloc((size_t)NN * 4);
    int*   bsum   = (int*)alloc(256 * 4);
    int*   col    = (int*)alloc((size_t)NEPAD * 4);
    float* cfv    = (float*)alloc((size_t)NEPAD * 4);
    float* t      = (float*)alloc((size_t)NN * HID * 4);   // slice-major
    float* rbuf   = (float*)alloc((size_t)NN * HID * 4);   // slice-major
    float* hA     = (float*)alloc((size_t)NN * HID * 4);
    float* hB     = (float*)alloc((size_t)NN * HID * 4);
    float* pooled = (float*)alloc((size_t)NGRAPH * HID * 4);
    // swizzled bf16 operands
    unsigned short* ahi  = (unsigned short*)alloc((size_t)ROWBLK_PAD * 4 * 512 * 2);
    unsigned short* alo  = (unsigned short*)alloc((size_t)ROWBLK_PAD * 4 * 512 * 2);
    unsigned short* bswH = (unsigned short*)alloc((size_t)7 * 16384 * 2);
    unsigned short* bswL = (unsigned short*)alloc((size_t)7 * 16384 * 2);

    hipMemsetAsync(deg, 0, (size_t)NN * 4, stream);
    hipMemsetAsync(cursor, 0, (size_t)NN * 4, stream);
    hipMemsetAsync(pooled, 0, (size_t)NGRAPH * HID * 4, stream);
    hipMemsetAsync(col, 0, (size_t)NEPAD * 4, stream);
    hipMemsetAsync(cfv, 0, (size_t)NEPAD * 4, stream);

    k_deg<<<NE / 256, 256, 0, stream>>>(ei, deg);
    k_dinv<<<(NN + 255) / 256, 256, 0, stream>>>(deg, dinv);
    k_scan1<<<(NN + 255) / 256, 256, 0, stream>>>(deg, bsum);
    k_scan2<<<1, 64, 0, stream>>>(bsum, (NN + 255) / 256);
    k_scan3<<<(NN + 255) / 256, 256, 0, stream>>>(deg, bsum, rowptr);
    k_fill<<<NE / 256, 256, 0, stream>>>(ei, rowptr, cursor, dinv, col, cfv);

    k_convB<<<dim3(8, 7), 256, 0, stream>>>(W0, Wh, Rh, bswH, bswL);

    const int spmmGrid = ROWBLK * NSLICE;  // 25000

    // initial block: t = x @ W0 ; hA = bn_relu(agg(t) + b0)
    k_convA<<<3125, 256, 0, stream>>>(x, ahi, alo);
    k_gemm_mfma<<<GEMM_GRID, 256, 0, stream>>>(ahi, alo, bswH, bswL, t);
    k_spmm<false><<<spmmGrid, 256, 0, stream>>>(t, nullptr, rowptr, deg, col, cfv,
                                                dinv, b0, g0, be0, hA);

    // residual blocks
    float* bufs[2] = {hA, hB};
    int cur = 0;
    for (int i = 0; i < LHID; ++i) {
        const float* hin = bufs[cur];
        float* hout = bufs[cur ^ 1];
        k_convA<<<3125, 256, 0, stream>>>(hin, ahi, alo);
        k_gemm_mfma<<<GEMM_GRID, 256, 0, stream>>>(
            ahi, alo, bswH + (size_t)(1 + i) * 16384, bswL + (size_t)(1 + i) * 16384, t);
        k_gemm_mfma<<<GEMM_GRID, 256, 0, stream>>>(
            ahi, alo, bswH + (size_t)(4 + i) * 16384, bswL + (size_t)(4 + i) * 16384, rbuf);
        k_spmm<true><<<spmmGrid, 256, 0, stream>>>(t, rbuf, rowptr, deg, col, cfv,
                                                   dinv, bh + i * HID, gh + i * HID,
                                                   beh + i * HID, hout);
        cur ^= 1;
    }

    k_pool<<<NGRAPH * 4, 128, 0, stream>>>(bufs[cur], batch, pooled);
    k_head<<<NGRAPH, 128, 0, stream>>>(pooled, mW1, mb1, mW2, mb2, out);
}

// Round 5
// 622.370 us; speedup vs baseline: 1.3671x; 1.3671x over previous
//
#include <hip/hip_runtime.h>
#include <cstdint>
#include <cstddef>

#define NN 50000
#define NN_PAD 50048          // GEMM row padding (391 blocks * 128 rows)
#define NE 800000
#define NEPAD (NE + 3 * NN)   // CSR rows padded to multiple of 4
#define HID 128
#define NGRAPH 64
#define NCLASS 10
#define LHID 3
#define GEMM_GRID 391         // 128-row tiles

// 1/sqrt(1+1e-5), computed in double, rounded to f32
static constexpr float BN_INV = 0.9999950000374996f;

typedef __attribute__((ext_vector_type(8))) __bf16 bf16x8;
typedef __attribute__((ext_vector_type(4))) float floatx4;
typedef __attribute__((ext_vector_type(4))) int intx4;

// ---------------- bf16 split helpers ----------------

__device__ __forceinline__ unsigned int f32_to_bf16_rne(float f) {
    unsigned int u = __float_as_uint(f);
    return (u + 0x7FFFu + ((u >> 16) & 1u)) >> 16;
}
__device__ __forceinline__ float bf16_to_f32(unsigned int h) {
    return __uint_as_float(h << 16);
}
// split x into hi(bf16) + lo(bf16); returns packed shorts
__device__ __forceinline__ void split2(float a, float b, unsigned int& hi,
                                       unsigned int& lo) {
    unsigned int h0 = f32_to_bf16_rne(a), h1 = f32_to_bf16_rne(b);
    unsigned int l0 = f32_to_bf16_rne(a - bf16_to_f32(h0));
    unsigned int l1 = f32_to_bf16_rne(b - bf16_to_f32(h1));
    hi = h0 | (h1 << 16);
    lo = l0 | (l1 << 16);
}

__device__ __forceinline__ void gl2lds16(const void* g, void* l) {
    __builtin_amdgcn_global_load_lds((__attribute__((address_space(1))) void*)g,
                                     (__attribute__((address_space(3))) void*)l,
                                     16, 0, 0);
}

// ---------------- graph build ----------------

__global__ void k_deg(const int* __restrict__ ei, int* __restrict__ deg) {
    int e = blockIdx.x * 256 + threadIdx.x;
    if (e < NE) atomicAdd(&deg[ei[NE + e]], 1);
}

__global__ void k_dinv(const int* __restrict__ deg, float* __restrict__ dinv) {
    int i = blockIdx.x * 256 + threadIdx.x;
    if (i < NN) dinv[i] = rsqrtf((float)(deg[i] + 1));  // +1 self-loop
}

// scans over padded degree deg4 = (deg+3)&~3 so every CSR row start is 16B-aligned

__global__ void k_scan1(const int* __restrict__ deg, int* __restrict__ bsum) {
    __shared__ int s[256];
    int i = blockIdx.x * 256 + threadIdx.x;
    s[threadIdx.x] = (i < NN) ? ((deg[i] + 3) & ~3) : 0;
    __syncthreads();
    for (int o = 128; o > 0; o >>= 1) {
        if (threadIdx.x < o) s[threadIdx.x] += s[threadIdx.x + o];
        __syncthreads();
    }
    if (threadIdx.x == 0) bsum[blockIdx.x] = s[0];
}

// parallel exclusive scan over block sums (nb <= 256), one 256-thread block
__global__ void k_scan2(int* __restrict__ bsum, int nb) {
    __shared__ int s[256];
    int i = threadIdx.x;
    int v = (i < nb) ? bsum[i] : 0;
    s[i] = v;
    __syncthreads();
    for (int o = 1; o < 256; o <<= 1) {
        int tv = (i >= o) ? s[i - o] : 0;
        __syncthreads();
        s[i] += tv;
        __syncthreads();
    }
    if (i < nb) bsum[i] = s[i] - v;  // exclusive
}

__global__ void k_scan3(const int* __restrict__ deg, const int* __restrict__ bsum,
                        int* __restrict__ rowptr) {
    __shared__ int s[256];
    int i = blockIdx.x * 256 + threadIdx.x;
    int v = (i < NN) ? ((deg[i] + 3) & ~3) : 0;
    s[threadIdx.x] = v;
    __syncthreads();
    for (int o = 1; o < 256; o <<= 1) {
        int tv = (threadIdx.x >= o) ? s[threadIdx.x - o] : 0;
        __syncthreads();
        s[threadIdx.x] += tv;
        __syncthreads();
    }
    if (i < NN) rowptr[i] = bsum[blockIdx.x] + s[threadIdx.x] - v;  // exclusive
}

__global__ void k_fill(const int* __restrict__ ei, const int* __restrict__ rowptr,
                       int* __restrict__ cursor, const float* __restrict__ dinv,
                       int* __restrict__ col, float* __restrict__ cfv) {
    int e = blockIdx.x * 256 + threadIdx.x;
    if (e >= NE) return;
    int s = ei[e];
    int d = ei[NE + e];
    int p = rowptr[d] + atomicAdd(&cursor[d], 1);
    col[p] = s;
    cfv[p] = dinv[s];
}

// ---------------- input conversion: x (f32 row-major) -> hi/lo bf16 row-major

__global__ void k_convX(const float* __restrict__ x, unsigned short* __restrict__ hi,
                        unsigned short* __restrict__ lo) {
    int u = blockIdx.x * 256 + threadIdx.x;  // one float4 / 4 features each
    float4 v = ((const float4*)x)[u];        // grid covers NN*32 exactly
    uint2 H, L;
    split2(v.x, v.y, H.x, L.x);
    split2(v.z, v.w, H.y, L.y);
    ((uint2*)hi)[u] = H;
    ((uint2*)lo)[u] = L;
}

// ---------------- weight conversion: W [k][n] f32 -> Bt [n][k] bf16 hi/lo ----
// 7 matrices: 0 = W0, 1..3 = Wh[i], 4..6 = Rh[i]; each 16384 elems.

__global__ void k_convB(const float* __restrict__ W0, const float* __restrict__ Wh,
                        const float* __restrict__ Rh, unsigned short* __restrict__ hi,
                        unsigned short* __restrict__ lo) {
    int mat = blockIdx.y;
    const float* src = (mat == 0) ? W0
                     : (mat <= 3) ? (Wh + (size_t)(mat - 1) * 16384)
                                  : (Rh + (size_t)(mat - 4) * 16384);
    int u = blockIdx.x * 256 + threadIdx.x;  // 0..2047: (n, kchunk of 8)
    int n = u >> 4;
    int k = (u & 15) * 8;
    union { unsigned int i[4]; uint4 v; } H, L;
#pragma unroll
    for (int j = 0; j < 4; ++j) {
        float a = src[(size_t)(k + 2 * j) * 128 + n];
        float b = src[(size_t)(k + 2 * j + 1) * 128 + n];
        split2(a, b, H.i[j], L.i[j]);
    }
    size_t base = ((size_t)mat * 16384 + (size_t)n * 128 + k) >> 3;  // uint4 units
    ((uint4*)hi)[base] = H.v;
    ((uint4*)lo)[base] = L.v;
}

// ---------------- MFMA GEMM: C = A @ B, split-bf16 3-product ----------------
// A: row-major bf16 hi/lo [NN_PAD][128]; Bt: [n][k] bf16 hi/lo (one matrix).
// global_load_lds does the fragment-layout transform: LDS dst = lane*16 fixed,
// source per-lane = row (lane&15), k-chunk (lane>>4)*8 — arbitrary gather.
// Block: 128 rows x 128 cols, 4 waves 2x2, wave tile 64x64 = 4x4 16x16x32 tiles.

__global__ __launch_bounds__(256, 2) void k_gemm_mfma(
    const unsigned short* __restrict__ Ahi, const unsigned short* __restrict__ Alo,
    const unsigned short* __restrict__ Bhi, const unsigned short* __restrict__ Blo,
    float* __restrict__ C) {
    __shared__ unsigned short lds[4 * 8192];  // 64 KB
    unsigned short* AhiS = lds;
    unsigned short* AloS = lds + 8192;
    unsigned short* BhiS = lds + 16384;
    unsigned short* BloS = lds + 24576;

    const int tid = threadIdx.x;
    const int wave = tid >> 6;
    const int lane = tid & 63;
    const int wm = wave & 1;
    const int wn = wave >> 1;
    const int row0 = blockIdx.x * 128;
    // per-lane source offset within a (16-row x 32-k) unit: row=lane&15, k=(lane>>4)*8
    const size_t aLane = (size_t)(lane & 15) * 128 + (size_t)(lane >> 4) * 8;

    floatx4 acc[4][4];
    floatx4 zero = {0.f, 0.f, 0.f, 0.f};
#pragma unroll
    for (int i = 0; i < 4; ++i)
#pragma unroll
        for (int j = 0; j < 4; ++j) acc[i][j] = zero;

    for (int kc = 0; kc < 2; ++kc) {
#pragma unroll
        for (int it = 0; it < 4; ++it) {
            int b = it * 4 + wave;        // 0..15 : rb/nb = b>>1, kb = b&1
            int rb = b >> 1;
            int kb = b & 1;
            size_t kOff = (size_t)kc * 64 + (size_t)kb * 32;
            size_t aOff = (size_t)(row0 + rb * 16) * 128 + kOff + aLane;
            size_t bOff = (size_t)(rb * 16) * 128 + kOff + aLane;  // rb = n-block
            int ldsOff = b * 512;  // wave-uniform base; HW adds lane*16B
            gl2lds16(Ahi + aOff, AhiS + ldsOff);
            gl2lds16(Alo + aOff, AloS + ldsOff);
            gl2lds16(Bhi + bOff, BhiS + ldsOff);
            gl2lds16(Blo + bOff, BloS + ldsOff);
        }
        __syncthreads();

#pragma unroll
        for (int kb = 0; kb < 2; ++kb) {
            bf16x8 aH[4], aL[4], bH[4], bL[4];
#pragma unroll
            for (int t = 0; t < 4; ++t) {
                aH[t] = *(const bf16x8*)(AhiS + ((wm * 4 + t) * 2 + kb) * 512 + lane * 8);
                bH[t] = *(const bf16x8*)(BhiS + ((wn * 4 + t) * 2 + kb) * 512 + lane * 8);
            }
#pragma unroll
            for (int tm = 0; tm < 4; ++tm)
#pragma unroll
                for (int tn = 0; tn < 4; ++tn)
                    acc[tm][tn] = __builtin_amdgcn_mfma_f32_16x16x32_bf16(
                        aH[tm], bH[tn], acc[tm][tn], 0, 0, 0);
#pragma unroll
            for (int t = 0; t < 4; ++t)
                bL[t] = *(const bf16x8*)(BloS + ((wn * 4 + t) * 2 + kb) * 512 + lane * 8);
#pragma unroll
            for (int tm = 0; tm < 4; ++tm)
#pragma unroll
                for (int tn = 0; tn < 4; ++tn)
                    acc[tm][tn] = __builtin_amdgcn_mfma_f32_16x16x32_bf16(
                        aH[tm], bL[tn], acc[tm][tn], 0, 0, 0);
#pragma unroll
            for (int t = 0; t < 4; ++t)
                aL[t] = *(const bf16x8*)(AloS + ((wm * 4 + t) * 2 + kb) * 512 + lane * 8);
#pragma unroll
            for (int tm = 0; tm < 4; ++tm)
#pragma unroll
                for (int tn = 0; tn < 4; ++tn)
                    acc[tm][tn] = __builtin_amdgcn_mfma_f32_16x16x32_bf16(
                        aL[tm], bH[tn], acc[tm][tn], 0, 0, 0);
        }
        __syncthreads();
    }

    // epilogue: C/D layout col = lane&15, row = (lane>>4)*4 + r
    const int quad = lane >> 4;
    const int col0 = lane & 15;
    const int rowBase = row0 + wm * 64;
#pragma unroll
    for (int tm = 0; tm < 4; ++tm) {
#pragma unroll
        for (int tn = 0; tn < 4; ++tn) {
            int col = wn * 64 + tn * 16 + col0;
#pragma unroll
            for (int r = 0; r < 4; ++r) {
                int row = rowBase + tm * 16 + quad * 4 + r;
                if (row < NN) C[(size_t)row * 128 + col] = acc[tm][tn][r];
            }
        }
    }
}

// ---------------- SpMM + epilogue + bf16-split output --------------------
// 2 nodes per wave, 32 lanes x float4 each: one gather instr = 1 KB (2 rows,
// 16 B/lane). unroll 2 -> 8 KB in flight/wave. Epilogue: bias [+res] + BN +
// ReLU, then write bf16 hi/lo row-major (next layer's GEMM A operand); last
// layer additionally writes f32 for pooling.

template <bool RES, bool LAST>
__global__ __launch_bounds__(256) void k_spmm(const float* __restrict__ t,
                                              const float* __restrict__ r,
                                              const int* __restrict__ rowptr,
                                              const int* __restrict__ deg,
                                              const int* __restrict__ col,
                                              const float* __restrict__ cfv,
                                              const float* __restrict__ dinv,
                                              const float* __restrict__ bias,
                                              const float* __restrict__ gamma,
                                              const float* __restrict__ beta,
                                              unsigned short* __restrict__ hHi,
                                              unsigned short* __restrict__ hLo,
                                              float* __restrict__ hout) {
    const int lane = threadIdx.x & 63;
    const int fl = lane & 31;                  // float4 index within row
    const int node = blockIdx.x * 8 + (threadIdx.x >> 6) * 2 + (lane >> 5);
    const float4* __restrict__ t4 = (const float4*)t;

    const int start = rowptr[node];            // multiple of 4 -> 16B-aligned
    const int cnt4 = (deg[node] + 3) >> 2;
    float4 ax = make_float4(0.f, 0.f, 0.f, 0.f);
#pragma unroll 2
    for (int q = 0; q < cnt4; ++q) {
        intx4 cs = __builtin_nontemporal_load((const intx4*)&col[start + q * 4]);
        floatx4 wv = __builtin_nontemporal_load((const floatx4*)&cfv[start + q * 4]);
        float4 v0 = t4[(size_t)cs.x * 32 + fl];
        float4 v1 = t4[(size_t)cs.y * 32 + fl];
        float4 v2 = t4[(size_t)cs.z * 32 + fl];
        float4 v3 = t4[(size_t)cs.w * 32 + fl];
        ax.x = fmaf(wv.x, v0.x, ax.x); ax.y = fmaf(wv.x, v0.y, ax.y);
        ax.z = fmaf(wv.x, v0.z, ax.z); ax.w = fmaf(wv.x, v0.w, ax.w);
        ax.x = fmaf(wv.y, v1.x, ax.x); ax.y = fmaf(wv.y, v1.y, ax.y);
        ax.z = fmaf(wv.y, v1.z, ax.z); ax.w = fmaf(wv.y, v1.w, ax.w);
        ax.x = fmaf(wv.z, v2.x, ax.x); ax.y = fmaf(wv.z, v2.y, ax.y);
        ax.z = fmaf(wv.z, v2.z, ax.z); ax.w = fmaf(wv.z, v2.w, ax.w);
        ax.x = fmaf(wv.w, v3.x, ax.x); ax.y = fmaf(wv.w, v3.y, ax.y);
        ax.z = fmaf(wv.w, v3.z, ax.z); ax.w = fmaf(wv.w, v3.w, ax.w);
    }
    const float di = dinv[node];
    const float dii = di * di;
    float4 tv = t4[(size_t)node * 32 + fl];
    float4 bv = *(const float4*)&bias[fl * 4];
    float4 cx;
    cx.x = di * ax.x + dii * tv.x + bv.x;
    cx.y = di * ax.y + dii * tv.y + bv.y;
    cx.z = di * ax.z + dii * tv.z + bv.z;
    cx.w = di * ax.w + dii * tv.w + bv.w;
    if (RES) {
        float4 rv = ((const float4*)r)[(size_t)node * 32 + fl];
        cx.x += rv.x; cx.y += rv.y; cx.z += rv.z; cx.w += rv.w;
    }
    float4 gv = *(const float4*)&gamma[fl * 4];
    float4 ev = *(const float4*)&beta[fl * 4];
    float4 o;
    o.x = fmaxf(cx.x * (BN_INV * gv.x) + ev.x, 0.f);
    o.y = fmaxf(cx.y * (BN_INV * gv.y) + ev.y, 0.f);
    o.z = fmaxf(cx.z * (BN_INV * gv.z) + ev.z, 0.f);
    o.w = fmaxf(cx.w * (BN_INV * gv.w) + ev.w, 0.f);

    const size_t idx = (size_t)node * 32 + fl;
    uint2 H, L;
    split2(o.x, o.y, H.x, L.x);
    split2(o.z, o.w, H.y, L.y);
    ((uint2*)hHi)[idx] = H;
    ((uint2*)hLo)[idx] = L;
    if (LAST) ((float4*)hout)[idx] = o;
}

// ---------------- pooling (segment max over sorted batch) ----------------

__device__ inline int lbound(const int* __restrict__ b, int v) {
    int lo = 0, hi = NN;
    while (lo < hi) {
        int mid = (lo + hi) >> 1;
        if (b[mid] < v) lo = mid + 1; else hi = mid;
    }
    return lo;
}

__global__ void k_pool(const float* __restrict__ h, const int* __restrict__ batch,
                       float* __restrict__ pooled) {
    __shared__ int sLo, sHi;
    int g = blockIdx.x >> 2;
    int ch = blockIdx.x & 3;
    if (threadIdx.x == 0) {
        sLo = lbound(batch, g);
        sHi = lbound(batch, g + 1);
    }
    __syncthreads();
    int lo = sLo, hi = sHi;
    int len = hi - lo;
    int per = (len + 3) >> 2;
    int s = lo + ch * per;
    int e = min(s + per, hi);
    float m = 0.0f;  // h >= 0 post-ReLU
    for (int i = s; i < e; ++i) m = fmaxf(m, h[(size_t)i * 128 + threadIdx.x]);
    if (s < e) atomicMax((unsigned int*)&pooled[g * 128 + threadIdx.x], __float_as_uint(m));
}

// ---------------- MLP head ----------------

__global__ void k_head(const float* __restrict__ pooled, const float* __restrict__ mW1,
                       const float* __restrict__ mb1, const float* __restrict__ mW2,
                       const float* __restrict__ mb2, float* __restrict__ out) {
    __shared__ float p[128];
    __shared__ float z[128];
    int g = blockIdx.x;
    int j = threadIdx.x;  // 128 threads
    p[j] = pooled[g * 128 + j];
    __syncthreads();
    float a = mb1[j];
#pragma unroll 8
    for (int k = 0; k < 128; ++k) a += p[k] * mW1[k * 128 + j];
    z[j] = fmaxf(a, 0.f);
    __syncthreads();
    if (j < NCLASS) {
        float o = mb2[j];
#pragma unroll 8
        for (int k = 0; k < 128; ++k) o += z[k] * mW2[k * NCLASS + j];
        out[g * NCLASS + j] = o;
    }
}

// ---------------- launcher ----------------

extern "C" void kernel_launch(void* const* d_in, const int* in_sizes, int n_in,
                              void* d_out, int out_size, void* d_ws, size_t ws_size,
                              hipStream_t stream) {
    const float* x   = (const float*)d_in[0];
    const int*   ei  = (const int*)d_in[1];
    const int* batch = (const int*)d_in[2];
    const float* W0  = (const float*)d_in[3];
    const float* b0  = (const float*)d_in[4];
    const float* g0  = (const float*)d_in[5];
    const float* be0 = (const float*)d_in[6];
    const float* Wh  = (const float*)d_in[7];
    const float* bh  = (const float*)d_in[8];
    const float* gh  = (const float*)d_in[9];
    const float* beh = (const float*)d_in[10];
    const float* Rh  = (const float*)d_in[11];
    const float* mW1 = (const float*)d_in[12];
    const float* mb1 = (const float*)d_in[13];
    const float* mW2 = (const float*)d_in[14];
    const float* mb2 = (const float*)d_in[15];
    float* out = (float*)d_out;

    char* ws = (char*)d_ws;
    size_t off = 0;
    auto alloc = [&](size_t bytes) -> void* {
        void* p = ws + off;
        off += (bytes + 255) & ~(size_t)255;
        return p;
    };
    int*   deg    = (int*)alloc((size_t)NN * 4);
    int*   rowptr = (int*)alloc((size_t)NN * 4);
    int*   cursor = (int*)alloc((size_t)NN * 4);
    float* dinv   = (float*)alloc((size_t)NN * 4);
    int*   bsum   = (int*)alloc(256 * 4);
    int*   col    = (int*)alloc((size_t)NEPAD * 4);
    float* cfv    = (float*)alloc((size_t)NEPAD * 4);
    float* t      = (float*)alloc((size_t)NN * HID * 4);
    float* rbuf   = (float*)alloc((size_t)NN * HID * 4);
    float* hF     = (float*)alloc((size_t)NN * HID * 4);
    float* pooled = (float*)alloc((size_t)NGRAPH * HID * 4);
    // bf16 hi/lo activations, row-major [NN_PAD][128], ping-pong A/B
    unsigned short* hiA = (unsigned short*)alloc((size_t)NN_PAD * HID * 2);
    unsigned short* loA = (unsigned short*)alloc((size_t)NN_PAD * HID * 2);
    unsigned short* hiB = (unsigned short*)alloc((size_t)NN_PAD * HID * 2);
    unsigned short* loB = (unsigned short*)alloc((size_t)NN_PAD * HID * 2);
    // transposed weights Bt [n][k] bf16 hi/lo, 7 matrices
    unsigned short* btH = (unsigned short*)alloc((size_t)7 * 16384 * 2);
    unsigned short* btL = (unsigned short*)alloc((size_t)7 * 16384 * 2);

    hipMemsetAsync(deg, 0, (size_t)NN * 4, stream);
    hipMemsetAsync(cursor, 0, (size_t)NN * 4, stream);
    hipMemsetAsync(pooled, 0, (size_t)NGRAPH * HID * 4, stream);
    hipMemsetAsync(col, 0, (size_t)NEPAD * 4, stream);
    hipMemsetAsync(cfv, 0, (size_t)NEPAD * 4, stream);

    k_deg<<<NE / 256, 256, 0, stream>>>(ei, deg);
    k_dinv<<<(NN + 255) / 256, 256, 0, stream>>>(deg, dinv);
    k_scan1<<<(NN + 255) / 256, 256, 0, stream>>>(deg, bsum);
    k_scan2<<<1, 256, 0, stream>>>(bsum, (NN + 255) / 256);
    k_scan3<<<(NN + 255) / 256, 256, 0, stream>>>(deg, bsum, rowptr);
    k_fill<<<NE / 256, 256, 0, stream>>>(ei, rowptr, cursor, dinv, col, cfv);

    k_convB<<<dim3(8, 7), 256, 0, stream>>>(W0, Wh, Rh, btH, btL);
    k_convX<<<NN * 32 / 256, 256, 0, stream>>>(x, hiA, loA);

    const int spmmGrid = NN / 8;  // 6250

    // initial block: t = x @ W0 ; h -> hiB/loB
    k_gemm_mfma<<<GEMM_GRID, 256, 0, stream>>>(hiA, loA, btH, btL, t);
    k_spmm<false, false><<<spmmGrid, 256, 0, stream>>>(
        t, nullptr, rowptr, deg, col, cfv, dinv, b0, g0, be0, hiB, loB, nullptr);

    // residual blocks (ping-pong hi/lo buffers)
    unsigned short* hi[2] = {hiB, hiA};
    unsigned short* lo[2] = {loB, loA};
    int cur = 0;
    for (int i = 0; i < LHID; ++i) {
        unsigned short* ih = hi[cur];
        unsigned short* il = lo[cur];
        unsigned short* oh = hi[cur ^ 1];
        unsigned short* ol = lo[cur ^ 1];
        k_gemm_mfma<<<GEMM_GRID, 256, 0, stream>>>(
            ih, il, btH + (size_t)(1 + i) * 16384, btL + (size_t)(1 + i) * 16384, t);
        k_gemm_mfma<<<GEMM_GRID, 256, 0, stream>>>(
            ih, il, btH + (size_t)(4 + i) * 16384, btL + (size_t)(4 + i) * 16384, rbuf);
        if (i < LHID - 1)
            k_spmm<true, false><<<spmmGrid, 256, 0, stream>>>(
                t, rbuf, rowptr, deg, col, cfv, dinv, bh + i * HID, gh + i * HID,
                beh + i * HID, oh, ol, nullptr);
        else
            k_spmm<true, true><<<spmmGrid, 256, 0, stream>>>(
                t, rbuf, rowptr, deg, col, cfv, dinv, bh + i * HID, gh + i * HID,
                beh + i * HID, oh, ol, hF);
        cur ^= 1;
    }

    k_pool<<<NGRAPH * 4, 128, 0, stream>>>(hF, batch, pooled);
    k_head<<<NGRAPH, 128, 0, stream>>>(pooled, mW1, mb1, mW2, mb2, out);
}

// Round 6
// 596.154 us; speedup vs baseline: 1.4273x; 1.0440x over previous
//
#include <hip/hip_runtime.h>
#include <cstdint>
#include <cstddef>

#define NN 50000
#define NE 800000
#define NEPAD (NE + 3 * NN)   // CSR rows padded to multiple of 4
#define HID 128
#define NGRAPH 64
#define NCLASS 10
#define LHID 3

// row-blocks of 16 rows: 50000/16 = 3125 exact; GEMM covers 391*8 = 3128
#define ROWBLK 3125
#define ROWBLK_PAD 3128
#define GEMM_GRID 391

// 1/sqrt(1+1e-5), computed in double, rounded to f32
static constexpr float BN_INV = 0.9999950000374996f;

typedef __attribute__((ext_vector_type(8))) __bf16 bf16x8;
typedef __attribute__((ext_vector_type(4))) float floatx4;

// ---------------- bf16 split helpers ----------------

__device__ __forceinline__ unsigned int f32_to_bf16_rne(float f) {
    unsigned int u = __float_as_uint(f);
    return (u + 0x7FFFu + ((u >> 16) & 1u)) >> 16;
}
__device__ __forceinline__ float bf16_to_f32(unsigned int h) {
    return __uint_as_float(h << 16);
}
__device__ __forceinline__ void split2(float a, float b, unsigned int& hi,
                                       unsigned int& lo) {
    unsigned int h0 = f32_to_bf16_rne(a), h1 = f32_to_bf16_rne(b);
    unsigned int l0 = f32_to_bf16_rne(a - bf16_to_f32(h0));
    unsigned int l1 = f32_to_bf16_rne(b - bf16_to_f32(h1));
    hi = h0 | (h1 << 16);
    lo = l0 | (l1 << 16);
}

__device__ __forceinline__ void gl2lds16(const void* g, void* l) {
    __builtin_amdgcn_global_load_lds((__attribute__((address_space(1))) void*)g,
                                     (__attribute__((address_space(3))) void*)l,
                                     16, 0, 0);
}

// ---------------- graph build ----------------

__global__ void k_deg(const int* __restrict__ ei, int* __restrict__ deg) {
    int e = blockIdx.x * 256 + threadIdx.x;
    if (e < NE) atomicAdd(&deg[ei[NE + e]], 1);
}

__global__ void k_dinv(const int* __restrict__ deg, float* __restrict__ dinv) {
    int i = blockIdx.x * 256 + threadIdx.x;
    if (i < NN) dinv[i] = rsqrtf((float)(deg[i] + 1));  // +1 self-loop
}

// scans over padded degree deg4 = (deg+3)&~3 so every CSR row start is 16B-aligned

__global__ void k_scan1(const int* __restrict__ deg, int* __restrict__ bsum) {
    __shared__ int s[256];
    int i = blockIdx.x * 256 + threadIdx.x;
    s[threadIdx.x] = (i < NN) ? ((deg[i] + 3) & ~3) : 0;
    __syncthreads();
    for (int o = 128; o > 0; o >>= 1) {
        if (threadIdx.x < o) s[threadIdx.x] += s[threadIdx.x + o];
        __syncthreads();
    }
    if (threadIdx.x == 0) bsum[blockIdx.x] = s[0];
}

__global__ void k_scan2(int* __restrict__ bsum, int nb) {
    __shared__ int s[256];
    int i = threadIdx.x;
    int v = (i < nb) ? bsum[i] : 0;
    s[i] = v;
    __syncthreads();
    for (int o = 1; o < 256; o <<= 1) {
        int tv = (i >= o) ? s[i - o] : 0;
        __syncthreads();
        s[i] += tv;
        __syncthreads();
    }
    if (i < nb) bsum[i] = s[i] - v;  // exclusive
}

__global__ void k_scan3(const int* __restrict__ deg, const int* __restrict__ bsum,
                        int* __restrict__ rowptr) {
    __shared__ int s[256];
    int i = blockIdx.x * 256 + threadIdx.x;
    int v = (i < NN) ? ((deg[i] + 3) & ~3) : 0;
    s[threadIdx.x] = v;
    __syncthreads();
    for (int o = 1; o < 256; o <<= 1) {
        int tv = (threadIdx.x >= o) ? s[threadIdx.x - o] : 0;
        __syncthreads();
        s[threadIdx.x] += tv;
        __syncthreads();
    }
    if (i < NN) rowptr[i] = bsum[blockIdx.x] + s[threadIdx.x] - v;  // exclusive
}

__global__ void k_fill(const int* __restrict__ ei, const int* __restrict__ rowptr,
                       int* __restrict__ cursor, const float* __restrict__ dinv,
                       int* __restrict__ col, float* __restrict__ cfv) {
    int e = blockIdx.x * 256 + threadIdx.x;
    if (e >= NE) return;
    int s = ei[e];
    int d = ei[NE + e];
    int p = rowptr[d] + atomicAdd(&cursor[d], 1);
    col[p] = s;
    cfv[p] = dinv[s];
}

// ---------------- converters: fp32 -> swizzled bf16 hi/lo ----------------
// A-operand fragment layout per (rowBlock of 16 m) x (kblk of 32 k) block:
//   lane = ((k>>3)&3)*16 + (m&15), holds 8 consecutive k (16 B).
// Flat: ((rowBlock*4 + kblk)*64 + lane)*8 elements.

__global__ void k_convA(const float* __restrict__ src, unsigned short* __restrict__ hi,
                        unsigned short* __restrict__ lo) {
    int u = blockIdx.x * 256 + threadIdx.x;  // one 16B output unit each
    int lane = u & 63;
    int blk = u >> 6;
    int kblk = blk & 3;
    int rowBlock = blk >> 2;
    int m = rowBlock * 16 + (lane & 15);
    int k = kblk * 32 + (lane >> 4) * 8;
    const float4* p = (const float4*)&src[(size_t)m * 128 + k];
    float4 v0 = p[0];
    float4 v1 = p[1];
    float vals[8] = {v0.x, v0.y, v0.z, v0.w, v1.x, v1.y, v1.z, v1.w};
    union { unsigned int i[4]; uint4 v; } H, L;
#pragma unroll
    for (int j = 0; j < 4; ++j) split2(vals[2 * j], vals[2 * j + 1], H.i[j], L.i[j]);
    *(uint4*)&hi[(size_t)u * 8] = H.v;
    *(uint4*)&lo[(size_t)u * 8] = L.v;
}

// B-operand: source W is [k][n] row-major (128x128). Same fragment layout with
// n in place of m. 7 matrices: 0 = W0, 1..3 = Wh[i], 4..6 = Rh[i].

__global__ void k_convB(const float* __restrict__ W0, const float* __restrict__ Wh,
                        const float* __restrict__ Rh, unsigned short* __restrict__ hi,
                        unsigned short* __restrict__ lo) {
    int mat = blockIdx.y;
    const float* src = (mat == 0) ? W0
                     : (mat <= 3) ? (Wh + (size_t)(mat - 1) * 16384)
                                  : (Rh + (size_t)(mat - 4) * 16384);
    int u = blockIdx.x * 256 + threadIdx.x;  // 0..2047
    int lane = u & 63;
    int blk = u >> 6;
    int kblk = blk & 3;
    int nb = blk >> 2;
    int n = nb * 16 + (lane & 15);
    int k = kblk * 32 + (lane >> 4) * 8;
    union { unsigned int i[4]; uint4 v; } H, L;
#pragma unroll
    for (int j = 0; j < 4; ++j) {
        float a = src[(size_t)(k + 2 * j) * 128 + n];
        float b = src[(size_t)(k + 2 * j + 1) * 128 + n];
        split2(a, b, H.i[j], L.i[j]);
    }
    size_t base = (size_t)mat * 16384 + (size_t)u * 8;
    *(uint4*)&hi[base] = H.v;
    *(uint4*)&lo[base] = L.v;
}

// ---------------- MFMA GEMM: C1 = A @ B1 [, C2 = A @ B2], split-bf16 --------
// A, B swizzled (fragment-order) -> staging is contiguous 1 KB global_load_lds.
// NB=2 fuses the per-layer W and R GEMMs: A staged ONCE for both products.
// Block: 128 rows x 128 cols (x NB), 4 waves 2x2, wave tile 64x64 per output.
// K in 4 chunks of 32. LDS = (2+2*NB)*8KB (NB=2: 48 KB).

template <int NB>
__global__ __launch_bounds__(256, 2) void k_gemm_mfma(
    const unsigned short* __restrict__ Ahi, const unsigned short* __restrict__ Alo,
    const unsigned short* __restrict__ B1hi, const unsigned short* __restrict__ B1lo,
    const unsigned short* __restrict__ B2hi, const unsigned short* __restrict__ B2lo,
    float* __restrict__ C1, float* __restrict__ C2) {
    __shared__ unsigned short lds[(2 + 2 * NB) * 4096];
    unsigned short* AhiS = lds;
    unsigned short* AloS = lds + 4096;
    unsigned short* B1hiS = lds + 2 * 4096;
    unsigned short* B1loS = lds + 3 * 4096;
    unsigned short* B2hiS = lds + 4 * 4096;  // NB==2 only
    unsigned short* B2loS = lds + 5 * 4096;

    const int tid = threadIdx.x;
    const int wave = tid >> 6;
    const int lane = tid & 63;
    const int wm = wave & 1;
    const int wn = wave >> 1;
    const int rb0 = blockIdx.x * 8;

    floatx4 acc1[4][4], acc2[4][4];
    floatx4 zero = {0.f, 0.f, 0.f, 0.f};
#pragma unroll
    for (int i = 0; i < 4; ++i)
#pragma unroll
        for (int j = 0; j < 4; ++j) { acc1[i][j] = zero; if (NB == 2) acc2[i][j] = zero; }

    for (int kc = 0; kc < 4; ++kc) {
        const int nit = (2 + 2 * NB) * 2;  // segs*8 / 4 waves
#pragma unroll
        for (int it = 0; it < nit; ++it) {
            int i = it * 4 + wave;
            int seg = i >> 3;
            int rb = i & 7;
            size_t aOff = ((size_t)(rb0 + rb) * 4 + kc) * 512 + (size_t)lane * 8;
            size_t bOff = ((size_t)rb * 4 + kc) * 512 + (size_t)lane * 8;
            unsigned short* dst = lds + seg * 4096 + rb * 512;
            if (seg == 0)      gl2lds16(Ahi + aOff, dst);
            else if (seg == 1) gl2lds16(Alo + aOff, dst);
            else if (seg == 2) gl2lds16(B1hi + bOff, dst);
            else if (seg == 3) gl2lds16(B1lo + bOff, dst);
            else if (seg == 4) gl2lds16(B2hi + bOff, dst);
            else               gl2lds16(B2lo + bOff, dst);
        }
        __syncthreads();

        bf16x8 aH[4], aL[4], bH[4], bL[4];
#pragma unroll
        for (int t = 0; t < 4; ++t) {
            aH[t] = *(const bf16x8*)(AhiS + (wm * 4 + t) * 512 + lane * 8);
            bH[t] = *(const bf16x8*)(B1hiS + (wn * 4 + t) * 512 + lane * 8);
        }
#pragma unroll
        for (int tm = 0; tm < 4; ++tm)
#pragma unroll
            for (int tn = 0; tn < 4; ++tn)
                acc1[tm][tn] = __builtin_amdgcn_mfma_f32_16x16x32_bf16(
                    aH[tm], bH[tn], acc1[tm][tn], 0, 0, 0);
#pragma unroll
        for (int t = 0; t < 4; ++t)
            bL[t] = *(const bf16x8*)(B1loS + (wn * 4 + t) * 512 + lane * 8);
#pragma unroll
        for (int tm = 0; tm < 4; ++tm)
#pragma unroll
            for (int tn = 0; tn < 4; ++tn)
                acc1[tm][tn] = __builtin_amdgcn_mfma_f32_16x16x32_bf16(
                    aH[tm], bL[tn], acc1[tm][tn], 0, 0, 0);
#pragma unroll
        for (int t = 0; t < 4; ++t)
            aL[t] = *(const bf16x8*)(AloS + (wm * 4 + t) * 512 + lane * 8);
#pragma unroll
        for (int tm = 0; tm < 4; ++tm)
#pragma unroll
            for (int tn = 0; tn < 4; ++tn)
                acc1[tm][tn] = __builtin_amdgcn_mfma_f32_16x16x32_bf16(
                    aL[tm], bH[tn], acc1[tm][tn], 0, 0, 0);
        if (NB == 2) {
#pragma unroll
            for (int t = 0; t < 4; ++t)
                bH[t] = *(const bf16x8*)(B2hiS + (wn * 4 + t) * 512 + lane * 8);
#pragma unroll
            for (int tm = 0; tm < 4; ++tm)
#pragma unroll
                for (int tn = 0; tn < 4; ++tn)
                    acc2[tm][tn] = __builtin_amdgcn_mfma_f32_16x16x32_bf16(
                        aH[tm], bH[tn], acc2[tm][tn], 0, 0, 0);
#pragma unroll
            for (int tm = 0; tm < 4; ++tm)
#pragma unroll
                for (int tn = 0; tn < 4; ++tn)
                    acc2[tm][tn] = __builtin_amdgcn_mfma_f32_16x16x32_bf16(
                        aL[tm], bH[tn], acc2[tm][tn], 0, 0, 0);
#pragma unroll
            for (int t = 0; t < 4; ++t)
                bL[t] = *(const bf16x8*)(B2loS + (wn * 4 + t) * 512 + lane * 8);
#pragma unroll
            for (int tm = 0; tm < 4; ++tm)
#pragma unroll
                for (int tn = 0; tn < 4; ++tn)
                    acc2[tm][tn] = __builtin_amdgcn_mfma_f32_16x16x32_bf16(
                        aH[tm], bL[tn], acc2[tm][tn], 0, 0, 0);
        }
        __syncthreads();
    }

    // epilogue: C/D layout col = lane&15, row = (lane>>4)*4 + r
    const int quad = lane >> 4;
    const int col0 = lane & 15;
    const int rowBase = rb0 * 16 + wm * 64;
#pragma unroll
    for (int tm = 0; tm < 4; ++tm) {
#pragma unroll
        for (int tn = 0; tn < 4; ++tn) {
            int col = wn * 64 + tn * 16 + col0;
#pragma unroll
            for (int r = 0; r < 4; ++r) {
                int row = rowBase + tm * 16 + quad * 4 + r;
                if (row < NN) {
                    C1[(size_t)row * 128 + col] = acc1[tm][tn][r];
                    if (NB == 2) C2[(size_t)row * 128 + col] = acc2[tm][tn][r];
                }
            }
        }
    }
}

// ---------------- SpMM + epilogue + swizzled bf16-split output --------------
// One node per wave, lane handles features (2l, 2l+1) via float2 -> each gather
// instr moves one full contiguous 512 B row. 4 independent gathers per q-iter,
// unroll 2. Epilogue: bias [+res] + BN + ReLU, split to bf16 hi/lo written in
// the GEMM A-fragment (swizzled) layout; last layer also writes f32 for pool.

template <bool RES, bool LAST>
__global__ __launch_bounds__(256) void k_spmm(const float* __restrict__ t,
                                              const float* __restrict__ r,
                                              const int* __restrict__ rowptr,
                                              const int* __restrict__ deg,
                                              const int* __restrict__ col,
                                              const float* __restrict__ cfv,
                                              const float* __restrict__ dinv,
                                              const float* __restrict__ bias,
                                              const float* __restrict__ gamma,
                                              const float* __restrict__ beta,
                                              unsigned short* __restrict__ hHi,
                                              unsigned short* __restrict__ hLo,
                                              float* __restrict__ hF) {
    const int lane = threadIdx.x & 63;
    const int node = blockIdx.x * 4 + (threadIdx.x >> 6);  // grid = NN/4 exact
    const int f = lane * 2;
    const int start = rowptr[node];          // multiple of 4 -> 16B-aligned
    const int cnt4 = (deg[node] + 3) >> 2;
    float ax = 0.f, ay = 0.f;
#pragma unroll 2
    for (int q = 0; q < cnt4; ++q) {
        int4 cs = *(const int4*)&col[start + q * 4];
        float4 wv = *(const float4*)&cfv[start + q * 4];
        float2 v0 = *(const float2*)&t[(size_t)cs.x * 128 + f];
        float2 v1 = *(const float2*)&t[(size_t)cs.y * 128 + f];
        float2 v2 = *(const float2*)&t[(size_t)cs.z * 128 + f];
        float2 v3 = *(const float2*)&t[(size_t)cs.w * 128 + f];
        ax = fmaf(wv.x, v0.x, ax); ay = fmaf(wv.x, v0.y, ay);
        ax = fmaf(wv.y, v1.x, ax); ay = fmaf(wv.y, v1.y, ay);
        ax = fmaf(wv.z, v2.x, ax); ay = fmaf(wv.z, v2.y, ay);
        ax = fmaf(wv.w, v3.x, ax); ay = fmaf(wv.w, v3.y, ay);
    }
    const float di = dinv[node];
    const float dii = di * di;
    float2 tv = *(const float2*)&t[(size_t)node * 128 + f];
    float2 bv = *(const float2*)&bias[f];
    float cx = di * ax + dii * tv.x + bv.x;
    float cy = di * ay + dii * tv.y + bv.y;
    if (RES) {
        float2 rv = *(const float2*)&r[(size_t)node * 128 + f];
        cx += rv.x;
        cy += rv.y;
    }
    float2 gv = *(const float2*)&gamma[f];
    float2 ev = *(const float2*)&beta[f];
    float ox = fmaxf(cx * (BN_INV * gv.x) + ev.x, 0.f);
    float oy = fmaxf(cy * (BN_INV * gv.y) + ev.y, 0.f);

    if (LAST) *(float2*)&hF[(size_t)node * 128 + f] = make_float2(ox, oy);

    // swizzled A-fragment write: unit = ((m>>4)*4 + kblk)*64 + kgrp*16 + (m&15)
    // kblk = lane>>4, kgrp = (lane>>2)&3, word-in-unit = lane&3
    unsigned int H, L;
    split2(ox, oy, H, L);
    size_t unit = ((size_t)(node >> 4) * 4 + (lane >> 4)) * 64 +
                  (size_t)((lane >> 2) & 3) * 16 + (node & 15);
    size_t uoff = unit * 4 + (lane & 3);
    ((unsigned int*)hHi)[uoff] = H;
    ((unsigned int*)hLo)[uoff] = L;
}

// ---------------- pooling (segment max over sorted batch) ----------------

__device__ inline int lbound(const int* __restrict__ b, int v) {
    int lo = 0, hi = NN;
    while (lo < hi) {
        int mid = (lo + hi) >> 1;
        if (b[mid] < v) lo = mid + 1; else hi = mid;
    }
    return lo;
}

__global__ void k_pool(const float* __restrict__ h, const int* __restrict__ batch,
                       float* __restrict__ pooled) {
    __shared__ int sLo, sHi;
    int g = blockIdx.x >> 2;
    int ch = blockIdx.x & 3;
    if (threadIdx.x == 0) {
        sLo = lbound(batch, g);
        sHi = lbound(batch, g + 1);
    }
    __syncthreads();
    int lo = sLo, hi = sHi;
    int len = hi - lo;
    int per = (len + 3) >> 2;
    int s = lo + ch * per;
    int e = min(s + per, hi);
    float m = 0.0f;  // h >= 0 post-ReLU
    for (int i = s; i < e; ++i) m = fmaxf(m, h[(size_t)i * 128 + threadIdx.x]);
    if (s < e) atomicMax((unsigned int*)&pooled[g * 128 + threadIdx.x], __float_as_uint(m));
}

// ---------------- MLP head ----------------

__global__ void k_head(const float* __restrict__ pooled, const float* __restrict__ mW1,
                       const float* __restrict__ mb1, const float* __restrict__ mW2,
                       const float* __restrict__ mb2, float* __restrict__ out) {
    __shared__ float p[128];
    __shared__ float z[128];
    int g = blockIdx.x;
    int j = threadIdx.x;  // 128 threads
    p[j] = pooled[g * 128 + j];
    __syncthreads();
    float a = mb1[j];
#pragma unroll 8
    for (int k = 0; k < 128; ++k) a += p[k] * mW1[k * 128 + j];
    z[j] = fmaxf(a, 0.f);
    __syncthreads();
    if (j < NCLASS) {
        float o = mb2[j];
#pragma unroll 8
        for (int k = 0; k < 128; ++k) o += z[k] * mW2[k * NCLASS + j];
        out[g * NCLASS + j] = o;
    }
}

// ---------------- launcher ----------------

extern "C" void kernel_launch(void* const* d_in, const int* in_sizes, int n_in,
                              void* d_out, int out_size, void* d_ws, size_t ws_size,
                              hipStream_t stream) {
    const float* x   = (const float*)d_in[0];
    const int*   ei  = (const int*)d_in[1];
    const int* batch = (const int*)d_in[2];
    const float* W0  = (const float*)d_in[3];
    const float* b0  = (const float*)d_in[4];
    const float* g0  = (const float*)d_in[5];
    const float* be0 = (const float*)d_in[6];
    const float* Wh  = (const float*)d_in[7];
    const float* bh  = (const float*)d_in[8];
    const float* gh  = (const float*)d_in[9];
    const float* beh = (const float*)d_in[10];
    const float* Rh  = (const float*)d_in[11];
    const float* mW1 = (const float*)d_in[12];
    const float* mb1 = (const float*)d_in[13];
    const float* mW2 = (const float*)d_in[14];
    const float* mb2 = (const float*)d_in[15];
    float* out = (float*)d_out;

    char* ws = (char*)d_ws;
    size_t off = 0;
    auto alloc = [&](size_t bytes) -> void* {
        void* p = ws + off;
        off += (bytes + 255) & ~(size_t)255;
        return p;
    };
    int*   deg    = (int*)alloc((size_t)NN * 4);
    int*   rowptr = (int*)alloc((size_t)NN * 4);
    int*   cursor = (int*)alloc((size_t)NN * 4);
    float* dinv   = (float*)alloc((size_t)NN * 4);
    int*   bsum   = (int*)alloc(256 * 4);
    int*   col    = (int*)alloc((size_t)NEPAD * 4);
    float* cfv    = (float*)alloc((size_t)NEPAD * 4);
    float* t      = (float*)alloc((size_t)NN * HID * 4);
    float* rbuf   = (float*)alloc((size_t)NN * HID * 4);
    float* hF     = (float*)alloc((size_t)NN * HID * 4);
    float* pooled = (float*)alloc((size_t)NGRAPH * HID * 4);
    // swizzled bf16 hi/lo activations: x + 2 ping-pong sets
    const size_t ASZ = (size_t)ROWBLK_PAD * 4 * 512;  // elements
    unsigned short* xH = (unsigned short*)alloc(ASZ * 2);
    unsigned short* xL = (unsigned short*)alloc(ASZ * 2);
    unsigned short* hH0 = (unsigned short*)alloc(ASZ * 2);
    unsigned short* hL0 = (unsigned short*)alloc(ASZ * 2);
    unsigned short* hH1 = (unsigned short*)alloc(ASZ * 2);
    unsigned short* hL1 = (unsigned short*)alloc(ASZ * 2);
    // swizzled weights, 7 matrices
    unsigned short* bH = (unsigned short*)alloc((size_t)7 * 16384 * 2);
    unsigned short* bL = (unsigned short*)alloc((size_t)7 * 16384 * 2);

    hipMemsetAsync(deg, 0, (size_t)NN * 4, stream);
    hipMemsetAsync(cursor, 0, (size_t)NN * 4, stream);
    hipMemsetAsync(pooled, 0, (size_t)NGRAPH * HID * 4, stream);
    hipMemsetAsync(col, 0, (size_t)NEPAD * 4, stream);
    hipMemsetAsync(cfv, 0, (size_t)NEPAD * 4, stream);

    k_deg<<<NE / 256, 256, 0, stream>>>(ei, deg);
    k_dinv<<<(NN + 255) / 256, 256, 0, stream>>>(deg, dinv);
    k_scan1<<<(NN + 255) / 256, 256, 0, stream>>>(deg, bsum);
    k_scan2<<<1, 256, 0, stream>>>(bsum, (NN + 255) / 256);
    k_scan3<<<(NN + 255) / 256, 256, 0, stream>>>(deg, bsum, rowptr);
    k_fill<<<NE / 256, 256, 0, stream>>>(ei, rowptr, cursor, dinv, col, cfv);

    k_convB<<<dim3(8, 7), 256, 0, stream>>>(W0, Wh, Rh, bH, bL);
    k_convA<<<ROWBLK, 256, 0, stream>>>(x, xH, xL);

    const int spmmGrid = NN / 4;  // 12500

    // initial block: t = x @ W0 ; h -> hH0/hL0 (swizzled)
    k_gemm_mfma<1><<<GEMM_GRID, 256, 0, stream>>>(xH, xL, bH, bL, nullptr, nullptr,
                                                  t, nullptr);
    k_spmm<false, false><<<spmmGrid, 256, 0, stream>>>(
        t, nullptr, rowptr, deg, col, cfv, dinv, b0, g0, be0, hH0, hL0, nullptr);

    // residual blocks: fused W/R GEMM, ping-pong swizzled buffers
    unsigned short* hh[2] = {hH0, hH1};
    unsigned short* hl[2] = {hL0, hL1};
    int cur = 0;
    for (int i = 0; i < LHID; ++i) {
        unsigned short* ih = hh[cur];
        unsigned short* il = hl[cur];
        unsigned short* oh = hh[cur ^ 1];
        unsigned short* ol = hl[cur ^ 1];
        const unsigned short* w1H = bH + (size_t)(1 + i) * 16384;
        const unsigned short* w1L = bL + (size_t)(1 + i) * 16384;
        const unsigned short* w2H = bH + (size_t)(4 + i) * 16384;
        const unsigned short* w2L = bL + (size_t)(4 + i) * 16384;
        k_gemm_mfma<2><<<GEMM_GRID, 256, 0, stream>>>(ih, il, w1H, w1L, w2H, w2L,
                                                      t, rbuf);
        if (i < LHID - 1)
            k_spmm<true, false><<<spmmGrid, 256, 0, stream>>>(
                t, rbuf, rowptr, deg, col, cfv, dinv, bh + i * HID, gh + i * HID,
                beh + i * HID, oh, ol, nullptr);
        else
            k_spmm<true, true><<<spmmGrid, 256, 0, stream>>>(
                t, rbuf, rowptr, deg, col, cfv, dinv, bh + i * HID, gh + i * HID,
                beh + i * HID, oh, ol, hF);
        cur ^= 1;
    }

    k_pool<<<NGRAPH * 4, 128, 0, stream>>>(hF, batch, pooled);
    k_head<<<NGRAPH, 128, 0, stream>>>(pooled, mW1, mb1, mW2, mb2, out);
}

// Round 7
// 596.044 us; speedup vs baseline: 1.4275x; 1.0002x over previous
//
#include <hip/hip_runtime.h>
#include <cstdint>
#include <cstddef>

#define NN 50000
#define NE 800000
#define NEPAD (NE + 3 * NN)   // CSR rows padded to multiple of 4
#define HID 128
#define NGRAPH 64
#define NCLASS 10
#define LHID 3

// 16-row fragment blocks: 50000/16 = 3125 exact; GEMM covers 782*4 = 3128
#define ROWBLK 3125
#define ROWBLK_PAD 3128
#define GEMM_GRID 782         // 64-row tiles

// 1/sqrt(1+1e-5), computed in double, rounded to f32
static constexpr float BN_INV = 0.9999950000374996f;

typedef __attribute__((ext_vector_type(8))) __bf16 bf16x8;
typedef __attribute__((ext_vector_type(4))) float floatx4;

// ---------------- bf16 split helpers ----------------

__device__ __forceinline__ unsigned int f32_to_bf16_rne(float f) {
    unsigned int u = __float_as_uint(f);
    return (u + 0x7FFFu + ((u >> 16) & 1u)) >> 16;
}
__device__ __forceinline__ float bf16_to_f32(unsigned int h) {
    return __uint_as_float(h << 16);
}
__device__ __forceinline__ void split2(float a, float b, unsigned int& hi,
                                       unsigned int& lo) {
    unsigned int h0 = f32_to_bf16_rne(a), h1 = f32_to_bf16_rne(b);
    unsigned int l0 = f32_to_bf16_rne(a - bf16_to_f32(h0));
    unsigned int l1 = f32_to_bf16_rne(b - bf16_to_f32(h1));
    hi = h0 | (h1 << 16);
    lo = l0 | (l1 << 16);
}

__device__ __forceinline__ void gl2lds16(const void* g, void* l) {
    __builtin_amdgcn_global_load_lds((__attribute__((address_space(1))) void*)g,
                                     (__attribute__((address_space(3))) void*)l,
                                     16, 0, 0);
}

// ---------------- graph build ----------------

__global__ void k_deg(const int* __restrict__ ei, int* __restrict__ deg) {
    int e = blockIdx.x * 256 + threadIdx.x;
    if (e < NE) atomicAdd(&deg[ei[NE + e]], 1);
}

// scan1 also computes dinv (fused former k_dinv). Scans use padded degree
// deg4 = (deg+3)&~3 so every CSR row start is 16B-aligned.

__global__ void k_scan1(const int* __restrict__ deg, float* __restrict__ dinv,
                        int* __restrict__ bsum) {
    __shared__ int s[256];
    int i = blockIdx.x * 256 + threadIdx.x;
    int d = (i < NN) ? deg[i] : 0;
    if (i < NN) dinv[i] = rsqrtf((float)(d + 1));  // +1 self-loop
    s[threadIdx.x] = (d + 3) & ~3;
    __syncthreads();
    for (int o = 128; o > 0; o >>= 1) {
        if (threadIdx.x < o) s[threadIdx.x] += s[threadIdx.x + o];
        __syncthreads();
    }
    if (threadIdx.x == 0) bsum[blockIdx.x] = s[0];
}

__global__ void k_scan2(int* __restrict__ bsum, int nb) {
    __shared__ int s[256];
    int i = threadIdx.x;
    int v = (i < nb) ? bsum[i] : 0;
    s[i] = v;
    __syncthreads();
    for (int o = 1; o < 256; o <<= 1) {
        int tv = (i >= o) ? s[i - o] : 0;
        __syncthreads();
        s[i] += tv;
        __syncthreads();
    }
    if (i < nb) bsum[i] = s[i] - v;  // exclusive
}

__global__ void k_scan3(const int* __restrict__ deg, const int* __restrict__ bsum,
                        int* __restrict__ rowptr) {
    __shared__ int s[256];
    int i = blockIdx.x * 256 + threadIdx.x;
    int v = (i < NN) ? ((deg[i] + 3) & ~3) : 0;
    s[threadIdx.x] = v;
    __syncthreads();
    for (int o = 1; o < 256; o <<= 1) {
        int tv = (threadIdx.x >= o) ? s[threadIdx.x - o] : 0;
        __syncthreads();
        s[threadIdx.x] += tv;
        __syncthreads();
    }
    if (i < NN) rowptr[i] = bsum[blockIdx.x] + s[threadIdx.x] - v;  // exclusive
}

__global__ void k_fill(const int* __restrict__ ei, const int* __restrict__ rowptr,
                       int* __restrict__ cursor, const float* __restrict__ dinv,
                       int* __restrict__ col, float* __restrict__ cfv) {
    int e = blockIdx.x * 256 + threadIdx.x;
    if (e >= NE) return;
    int s = ei[e];
    int d = ei[NE + e];
    int p = rowptr[d] + atomicAdd(&cursor[d], 1);
    col[p] = s;
    cfv[p] = dinv[s];
}

// ---------------- converters: fp32 -> swizzled bf16 hi/lo ----------------
// A-operand fragment layout per (rowBlock of 16 m) x (kblk of 32 k) block:
//   lane = ((k>>3)&3)*16 + (m&15), holds 8 consecutive k (16 B).
// Flat: ((rowBlock*4 + kblk)*64 + lane)*8 elements.

__global__ void k_convA(const float* __restrict__ src, unsigned short* __restrict__ hi,
                        unsigned short* __restrict__ lo) {
    int u = blockIdx.x * 256 + threadIdx.x;  // one 16B output unit each
    int lane = u & 63;
    int blk = u >> 6;
    int kblk = blk & 3;
    int rowBlock = blk >> 2;
    int m = rowBlock * 16 + (lane & 15);
    int k = kblk * 32 + (lane >> 4) * 8;
    const float4* p = (const float4*)&src[(size_t)m * 128 + k];
    float4 v0 = p[0];
    float4 v1 = p[1];
    float vals[8] = {v0.x, v0.y, v0.z, v0.w, v1.x, v1.y, v1.z, v1.w};
    union { unsigned int i[4]; uint4 v; } H, L;
#pragma unroll
    for (int j = 0; j < 4; ++j) split2(vals[2 * j], vals[2 * j + 1], H.i[j], L.i[j]);
    *(uint4*)&hi[(size_t)u * 8] = H.v;
    *(uint4*)&lo[(size_t)u * 8] = L.v;
}

// B-operand: source W is [k][n] row-major (128x128). Same fragment layout with
// n in place of m. 7 matrices: 0 = W0, 1..3 = Wh[i], 4..6 = Rh[i].

__global__ void k_convB(const float* __restrict__ W0, const float* __restrict__ Wh,
                        const float* __restrict__ Rh, unsigned short* __restrict__ hi,
                        unsigned short* __restrict__ lo) {
    int mat = blockIdx.y;
    const float* src = (mat == 0) ? W0
                     : (mat <= 3) ? (Wh + (size_t)(mat - 1) * 16384)
                                  : (Rh + (size_t)(mat - 4) * 16384);
    int u = blockIdx.x * 256 + threadIdx.x;  // 0..2047
    int lane = u & 63;
    int blk = u >> 6;
    int kblk = blk & 3;
    int nb = blk >> 2;
    int n = nb * 16 + (lane & 15);
    int k = kblk * 32 + (lane >> 4) * 8;
    union { unsigned int i[4]; uint4 v; } H, L;
#pragma unroll
    for (int j = 0; j < 4; ++j) {
        float a = src[(size_t)(k + 2 * j) * 128 + n];
        float b = src[(size_t)(k + 2 * j + 1) * 128 + n];
        split2(a, b, H.i[j], L.i[j]);
    }
    size_t base = (size_t)mat * 16384 + (size_t)u * 8;
    *(uint4*)&hi[base] = H.v;
    *(uint4*)&lo[base] = L.v;
}

// ---------------- MFMA GEMM: C1 = A @ B1 [, C2 = A @ B2], split-bf16 --------
// 64 rows x 128 cols per output tile -> grid 782 ~= 3 blocks/CU x 256 CUs for
// packing + 3 waves/SIMD latency hiding (R6's 128-row tile gave 391 blocks =
// 1.5 waves/SIMD). 4 waves 2x2: wave tile 32x64 = 2x4 mfma 16x16x32 tiles.
// K in 4 chunks of 32. LDS = A(8KB) + B(16KB*NB): NB=2 -> 40 KB.

template <int NB>
__global__ __launch_bounds__(256, 3) void k_gemm_mfma(
    const unsigned short* __restrict__ Ahi, const unsigned short* __restrict__ Alo,
    const unsigned short* __restrict__ B1hi, const unsigned short* __restrict__ B1lo,
    const unsigned short* __restrict__ B2hi, const unsigned short* __restrict__ B2lo,
    float* __restrict__ C1, float* __restrict__ C2) {
    __shared__ unsigned short lds[(1 + 2 * NB) * 4096];
    unsigned short* AhiS = lds;             // 2048
    unsigned short* AloS = lds + 2048;      // 2048
    unsigned short* B1hiS = lds + 4096;     // 4096
    unsigned short* B1loS = lds + 8192;     // 4096
    unsigned short* B2hiS = lds + 12288;    // NB==2 only
    unsigned short* B2loS = lds + 16384;

    const int tid = threadIdx.x;
    const int wave = tid >> 6;
    const int lane = tid & 63;
    const int wm = wave & 1;
    const int wn = wave >> 1;
    const int rb0 = blockIdx.x * 4;         // first 16-row block

    floatx4 acc1[2][4], acc2[2][4];
    floatx4 zero = {0.f, 0.f, 0.f, 0.f};
#pragma unroll
    for (int i = 0; i < 2; ++i)
#pragma unroll
        for (int j = 0; j < 4; ++j) { acc1[i][j] = zero; if (NB == 2) acc2[i][j] = zero; }

    for (int kc = 0; kc < 4; ++kc) {
        const int nit = (NB == 2) ? 10 : 6;  // units: A 8 + B 16*NB, / 4 waves
#pragma unroll
        for (int it = 0; it < nit; ++it) {
            int i = it * 4 + wave;
            const unsigned short* src;
            unsigned short* dst;
            if (i < 4)       { src = Ahi  + ((size_t)(rb0 + i) * 4 + kc) * 512;       dst = AhiS  + i * 512; }
            else if (i < 8)  { int rb = i - 4;  src = Alo  + ((size_t)(rb0 + rb) * 4 + kc) * 512; dst = AloS  + rb * 512; }
            else if (i < 16) { int nb = i - 8;  src = B1hi + ((size_t)nb * 4 + kc) * 512;         dst = B1hiS + nb * 512; }
            else if (i < 24) { int nb = i - 16; src = B1lo + ((size_t)nb * 4 + kc) * 512;         dst = B1loS + nb * 512; }
            else if (i < 32) { int nb = i - 24; src = B2hi + ((size_t)nb * 4 + kc) * 512;         dst = B2hiS + nb * 512; }
            else             { int nb = i - 32; src = B2lo + ((size_t)nb * 4 + kc) * 512;         dst = B2loS + nb * 512; }
            gl2lds16(src + (size_t)lane * 8, dst);
        }
        __syncthreads();

        bf16x8 aH[2], aL[2], bH[4], bL[4];
#pragma unroll
        for (int t = 0; t < 2; ++t)
            aH[t] = *(const bf16x8*)(AhiS + (wm * 2 + t) * 512 + lane * 8);
#pragma unroll
        for (int t = 0; t < 4; ++t)
            bH[t] = *(const bf16x8*)(B1hiS + (wn * 4 + t) * 512 + lane * 8);
#pragma unroll
        for (int tm = 0; tm < 2; ++tm)
#pragma unroll
            for (int tn = 0; tn < 4; ++tn)
                acc1[tm][tn] = __builtin_amdgcn_mfma_f32_16x16x32_bf16(
                    aH[tm], bH[tn], acc1[tm][tn], 0, 0, 0);
#pragma unroll
        for (int t = 0; t < 4; ++t)
            bL[t] = *(const bf16x8*)(B1loS + (wn * 4 + t) * 512 + lane * 8);
#pragma unroll
        for (int tm = 0; tm < 2; ++tm)
#pragma unroll
            for (int tn = 0; tn < 4; ++tn)
                acc1[tm][tn] = __builtin_amdgcn_mfma_f32_16x16x32_bf16(
                    aH[tm], bL[tn], acc1[tm][tn], 0, 0, 0);
#pragma unroll
        for (int t = 0; t < 2; ++t)
            aL[t] = *(const bf16x8*)(AloS + (wm * 2 + t) * 512 + lane * 8);
#pragma unroll
        for (int tm = 0; tm < 2; ++tm)
#pragma unroll
            for (int tn = 0; tn < 4; ++tn)
                acc1[tm][tn] = __builtin_amdgcn_mfma_f32_16x16x32_bf16(
                    aL[tm], bH[tn], acc1[tm][tn], 0, 0, 0);
        if (NB == 2) {
#pragma unroll
            for (int t = 0; t < 4; ++t)
                bH[t] = *(const bf16x8*)(B2hiS + (wn * 4 + t) * 512 + lane * 8);
#pragma unroll
            for (int tm = 0; tm < 2; ++tm)
#pragma unroll
                for (int tn = 0; tn < 4; ++tn)
                    acc2[tm][tn] = __builtin_amdgcn_mfma_f32_16x16x32_bf16(
                        aH[tm], bH[tn], acc2[tm][tn], 0, 0, 0);
#pragma unroll
            for (int tm = 0; tm < 2; ++tm)
#pragma unroll
                for (int tn = 0; tn < 4; ++tn)
                    acc2[tm][tn] = __builtin_amdgcn_mfma_f32_16x16x32_bf16(
                        aL[tm], bH[tn], acc2[tm][tn], 0, 0, 0);
#pragma unroll
            for (int t = 0; t < 4; ++t)
                bL[t] = *(const bf16x8*)(B2loS + (wn * 4 + t) * 512 + lane * 8);
#pragma unroll
            for (int tm = 0; tm < 2; ++tm)
#pragma unroll
                for (int tn = 0; tn < 4; ++tn)
                    acc2[tm][tn] = __builtin_amdgcn_mfma_f32_16x16x32_bf16(
                        aH[tm], bL[tn], acc2[tm][tn], 0, 0, 0);
        }
        __syncthreads();
    }

    // epilogue: C/D layout col = lane&15, row = (lane>>4)*4 + r
    const int quad = lane >> 4;
    const int col0 = lane & 15;
    const int rowBase = blockIdx.x * 64 + wm * 32;
#pragma unroll
    for (int tm = 0; tm < 2; ++tm) {
#pragma unroll
        for (int tn = 0; tn < 4; ++tn) {
            int col = wn * 64 + tn * 16 + col0;
#pragma unroll
            for (int r = 0; r < 4; ++r) {
                int row = rowBase + tm * 16 + quad * 4 + r;
                if (row < NN) {
                    C1[(size_t)row * 128 + col] = acc1[tm][tn][r];
                    if (NB == 2) C2[(size_t)row * 128 + col] = acc2[tm][tn][r];
                }
            }
        }
    }
}

// ---------------- SpMM + epilogue + LDS-staged swizzled output --------------
// Block = 16 nodes: 4 waves x 4 serial nodes. Gather: 1 node/wave, lane ->
// features (2l,2l+1), one 512 B contiguous row per gather instr (R3's proven
// shape). Epilogue results go through a padded LDS tile; the block then emits
// the 8 swizzled A-fragment units (hi+lo) as one coalesced uint4 store per
// thread per buffer — kills R6's 2x write-line amplification.

template <bool RES, bool LAST>
__global__ __launch_bounds__(256) void k_spmm(const float* __restrict__ t,
                                              const float* __restrict__ r,
                                              const int* __restrict__ rowptr,
                                              const int* __restrict__ deg,
                                              const int* __restrict__ col,
                                              const float* __restrict__ cfv,
                                              const float* __restrict__ dinv,
                                              const float* __restrict__ bias,
                                              const float* __restrict__ gamma,
                                              const float* __restrict__ beta,
                                              unsigned short* __restrict__ hHi,
                                              unsigned short* __restrict__ hLo,
                                              float* __restrict__ hF) {
    __shared__ unsigned short shH[16][136];  // +8 shorts pad: 16B-aligned rows,
    __shared__ unsigned short shL[16][136];  // conflict-free swizzled reads
    const int lane = threadIdx.x & 63;
    const int wave = threadIdx.x >> 6;
    const int f = lane * 2;
    const float2 bv = *(const float2*)&bias[f];
    const float2 gv = *(const float2*)&gamma[f];
    const float2 ev = *(const float2*)&beta[f];

#pragma unroll 1
    for (int i = 0; i < 4; ++i) {
        const int nl = wave * 4 + i;
        const int node = blockIdx.x * 16 + nl;   // grid = NN/16 exact
        const int start = rowptr[node];          // multiple of 4, 16B-aligned
        const int cnt4 = (deg[node] + 3) >> 2;
        float ax = 0.f, ay = 0.f;
#pragma unroll 2
        for (int q = 0; q < cnt4; ++q) {
            int4 cs = *(const int4*)&col[start + q * 4];
            float4 wv = *(const float4*)&cfv[start + q * 4];
            float2 v0 = *(const float2*)&t[(size_t)cs.x * 128 + f];
            float2 v1 = *(const float2*)&t[(size_t)cs.y * 128 + f];
            float2 v2 = *(const float2*)&t[(size_t)cs.z * 128 + f];
            float2 v3 = *(const float2*)&t[(size_t)cs.w * 128 + f];
            ax = fmaf(wv.x, v0.x, ax); ay = fmaf(wv.x, v0.y, ay);
            ax = fmaf(wv.y, v1.x, ax); ay = fmaf(wv.y, v1.y, ay);
            ax = fmaf(wv.z, v2.x, ax); ay = fmaf(wv.z, v2.y, ay);
            ax = fmaf(wv.w, v3.x, ax); ay = fmaf(wv.w, v3.y, ay);
        }
        const float di = dinv[node];
        const float dii = di * di;
        float2 tv = *(const float2*)&t[(size_t)node * 128 + f];
        float cx = di * ax + dii * tv.x + bv.x;
        float cy = di * ay + dii * tv.y + bv.y;
        if (RES) {
            float2 rv = *(const float2*)&r[(size_t)node * 128 + f];
            cx += rv.x;
            cy += rv.y;
        }
        float ox = fmaxf(cx * (BN_INV * gv.x) + ev.x, 0.f);
        float oy = fmaxf(cy * (BN_INV * gv.y) + ev.y, 0.f);
        if (LAST) *(float2*)&hF[(size_t)node * 128 + f] = make_float2(ox, oy);
        unsigned int H, L;
        split2(ox, oy, H, L);
        ((unsigned int*)&shH[nl][0])[lane] = H;
        ((unsigned int*)&shL[nl][0])[lane] = L;
    }
    __syncthreads();

    // emit 4 hi + 4 lo units (1 KB each): unit = blockIdx*4 + kblk,
    // lane l holds (m = l&15, kgrp = l>>4) -> shX[m][kblk*32 + kgrp*8 .. +8]
    const int u = threadIdx.x >> 6;   // kblk
    const int l = threadIdx.x & 63;
    const int m = l & 15;
    const int kg = l >> 4;
    uint4 H4 = *(const uint4*)&shH[m][u * 32 + kg * 8];
    uint4 L4 = *(const uint4*)&shL[m][u * 32 + kg * 8];
    ((uint4*)hHi)[((size_t)blockIdx.x * 4 + u) * 64 + l] = H4;
    ((uint4*)hLo)[((size_t)blockIdx.x * 4 + u) * 64 + l] = L4;
}

// ---------------- pooling (segment max over sorted batch) ----------------

__device__ inline int lbound(const int* __restrict__ b, int v) {
    int lo = 0, hi = NN;
    while (lo < hi) {
        int mid = (lo + hi) >> 1;
        if (b[mid] < v) lo = mid + 1; else hi = mid;
    }
    return lo;
}

__global__ void k_pool(const float* __restrict__ h, const int* __restrict__ batch,
                       float* __restrict__ pooled) {
    __shared__ int sLo, sHi;
    int g = blockIdx.x >> 2;
    int ch = blockIdx.x & 3;
    if (threadIdx.x == 0) {
        sLo = lbound(batch, g);
        sHi = lbound(batch, g + 1);
    }
    __syncthreads();
    int lo = sLo, hi = sHi;
    int len = hi - lo;
    int per = (len + 3) >> 2;
    int s = lo + ch * per;
    int e = min(s + per, hi);
    float m = 0.0f;  // h >= 0 post-ReLU
    for (int i = s; i < e; ++i) m = fmaxf(m, h[(size_t)i * 128 + threadIdx.x]);
    if (s < e) atomicMax((unsigned int*)&pooled[g * 128 + threadIdx.x], __float_as_uint(m));
}

// ---------------- MLP head ----------------

__global__ void k_head(const float* __restrict__ pooled, const float* __restrict__ mW1,
                       const float* __restrict__ mb1, const float* __restrict__ mW2,
                       const float* __restrict__ mb2, float* __restrict__ out) {
    __shared__ float p[128];
    __shared__ float z[128];
    int g = blockIdx.x;
    int j = threadIdx.x;  // 128 threads
    p[j] = pooled[g * 128 + j];
    __syncthreads();
    float a = mb1[j];
#pragma unroll 8
    for (int k = 0; k < 128; ++k) a += p[k] * mW1[k * 128 + j];
    z[j] = fmaxf(a, 0.f);
    __syncthreads();
    if (j < NCLASS) {
        float o = mb2[j];
#pragma unroll 8
        for (int k = 0; k < 128; ++k) o += z[k] * mW2[k * NCLASS + j];
        out[g * NCLASS + j] = o;
    }
}

// ---------------- launcher ----------------

extern "C" void kernel_launch(void* const* d_in, const int* in_sizes, int n_in,
                              void* d_out, int out_size, void* d_ws, size_t ws_size,
                              hipStream_t stream) {
    const float* x   = (const float*)d_in[0];
    const int*   ei  = (const int*)d_in[1];
    const int* batch = (const int*)d_in[2];
    const float* W0  = (const float*)d_in[3];
    const float* b0  = (const float*)d_in[4];
    const float* g0  = (const float*)d_in[5];
    const float* be0 = (const float*)d_in[6];
    const float* Wh  = (const float*)d_in[7];
    const float* bh  = (const float*)d_in[8];
    const float* gh  = (const float*)d_in[9];
    const float* beh = (const float*)d_in[10];
    const float* Rh  = (const float*)d_in[11];
    const float* mW1 = (const float*)d_in[12];
    const float* mb1 = (const float*)d_in[13];
    const float* mW2 = (const float*)d_in[14];
    const float* mb2 = (const float*)d_in[15];
    float* out = (float*)d_out;

    char* ws = (char*)d_ws;
    size_t off = 0;
    auto alloc = [&](size_t bytes) -> void* {
        void* p = ws + off;
        off += (bytes + 255) & ~(size_t)255;
        return p;
    };
    int*   deg    = (int*)alloc((size_t)NN * 4);
    int*   rowptr = (int*)alloc((size_t)NN * 4);
    int*   cursor = (int*)alloc((size_t)NN * 4);
    float* dinv   = (float*)alloc((size_t)NN * 4);
    int*   bsum   = (int*)alloc(256 * 4);
    int*   col    = (int*)alloc((size_t)NEPAD * 4);
    float* cfv    = (float*)alloc((size_t)NEPAD * 4);
    float* t      = (float*)alloc((size_t)NN * HID * 4);
    float* rbuf   = (float*)alloc((size_t)NN * HID * 4);
    float* hF     = (float*)alloc((size_t)NN * HID * 4);
    float* pooled = (float*)alloc((size_t)NGRAPH * HID * 4);
    // swizzled bf16 hi/lo activations: x + 2 ping-pong sets
    const size_t ASZ = (size_t)ROWBLK_PAD * 4 * 512;  // elements
    unsigned short* xH = (unsigned short*)alloc(ASZ * 2);
    unsigned short* xL = (unsigned short*)alloc(ASZ * 2);
    unsigned short* hH0 = (unsigned short*)alloc(ASZ * 2);
    unsigned short* hL0 = (unsigned short*)alloc(ASZ * 2);
    unsigned short* hH1 = (unsigned short*)alloc(ASZ * 2);
    unsigned short* hL1 = (unsigned short*)alloc(ASZ * 2);
    // swizzled weights, 7 matrices
    unsigned short* bH = (unsigned short*)alloc((size_t)7 * 16384 * 2);
    unsigned short* bL = (unsigned short*)alloc((size_t)7 * 16384 * 2);

    hipMemsetAsync(deg, 0, (size_t)NN * 4, stream);
    hipMemsetAsync(cursor, 0, (size_t)NN * 4, stream);
    hipMemsetAsync(pooled, 0, (size_t)NGRAPH * HID * 4, stream);
    hipMemsetAsync(col, 0, (size_t)NEPAD * 4, stream);
    hipMemsetAsync(cfv, 0, (size_t)NEPAD * 4, stream);

    k_deg<<<NE / 256, 256, 0, stream>>>(ei, deg);
    k_scan1<<<(NN + 255) / 256, 256, 0, stream>>>(deg, dinv, bsum);
    k_scan2<<<1, 256, 0, stream>>>(bsum, (NN + 255) / 256);
    k_scan3<<<(NN + 255) / 256, 256, 0, stream>>>(deg, bsum, rowptr);
    k_fill<<<NE / 256, 256, 0, stream>>>(ei, rowptr, cursor, dinv, col, cfv);

    k_convB<<<dim3(8, 7), 256, 0, stream>>>(W0, Wh, Rh, bH, bL);
    k_convA<<<ROWBLK, 256, 0, stream>>>(x, xH, xL);

    const int spmmGrid = NN / 16;  // 3125

    // initial block: t = x @ W0 ; h -> hH0/hL0 (swizzled)
    k_gemm_mfma<1><<<GEMM_GRID, 256, 0, stream>>>(xH, xL, bH, bL, nullptr, nullptr,
                                                  t, nullptr);
    k_spmm<false, false><<<spmmGrid, 256, 0, stream>>>(
        t, nullptr, rowptr, deg, col, cfv, dinv, b0, g0, be0, hH0, hL0, nullptr);

    // residual blocks: fused W/R GEMM, ping-pong swizzled buffers
    unsigned short* hh[2] = {hH0, hH1};
    unsigned short* hl[2] = {hL0, hL1};
    int cur = 0;
    for (int i = 0; i < LHID; ++i) {
        unsigned short* ih = hh[cur];
        unsigned short* il = hl[cur];
        unsigned short* oh = hh[cur ^ 1];
        unsigned short* ol = hl[cur ^ 1];
        const unsigned short* w1H = bH + (size_t)(1 + i) * 16384;
        const unsigned short* w1L = bL + (size_t)(1 + i) * 16384;
        const unsigned short* w2H = bH + (size_t)(4 + i) * 16384;
        const unsigned short* w2L = bL + (size_t)(4 + i) * 16384;
        k_gemm_mfma<2><<<GEMM_GRID, 256, 0, stream>>>(ih, il, w1H, w1L, w2H, w2L,
                                                      t, rbuf);
        if (i < LHID - 1)
            k_spmm<true, false><<<spmmGrid, 256, 0, stream>>>(
                t, rbuf, rowptr, deg, col, cfv, dinv, bh + i * HID, gh + i * HID,
                beh + i * HID, oh, ol, nullptr);
        else
            k_spmm<true, true><<<spmmGrid, 256, 0, stream>>>(
                t, rbuf, rowptr, deg, col, cfv, dinv, bh + i * HID, gh + i * HID,
                beh + i * HID, oh, ol, hF);
        cur ^= 1;
    }

    k_pool<<<NGRAPH * 4, 128, 0, stream>>>(hF, batch, pooled);
    k_head<<<NGRAPH, 128, 0, stream>>>(pooled, mW1, mb1, mW2, mb2, out);
}

// Round 9
// 526.304 us; speedup vs baseline: 1.6167x; 1.1325x over previous
//
#include <hip/hip_runtime.h>
#include <cstdint>
#include <cstddef>

#define NN 50000
#define NE 800000
#define NEPAD (NE + 3 * NN)   // CSR rows padded to multiple of 4
#define HID 128
#define NGRAPH 64
#define NCLASS 10
#define LHID 3

// 16-row fragment blocks: 50000/16 = 3125 exact; GEMM covers 782*4 = 3128
#define ROWBLK 3125
#define ROWBLK_PAD 3128
#define GEMM_GRID 782         // 64-row tiles
#define FILL_GRID 3125        // 800000 / 256
#define FRONT_A 3125          // convA blocks
#define FRONT_B 56            // convB blocks (8 x 7 mats)
#define FRONT_GRID (FRONT_A + FRONT_B + 3125)

// 1/sqrt(1+1e-5), computed in double, rounded to f32
static constexpr float BN_INV = 0.9999950000374996f;

typedef __attribute__((ext_vector_type(8))) __bf16 bf16x8;
typedef __attribute__((ext_vector_type(4))) float floatx4;

// ---------------- bf16 split helpers ----------------

__device__ __forceinline__ unsigned int f32_to_bf16_rne(float f) {
    unsigned int u = __float_as_uint(f);
    return (u + 0x7FFFu + ((u >> 16) & 1u)) >> 16;
}
__device__ __forceinline__ float bf16_to_f32(unsigned int h) {
    return __uint_as_float(h << 16);
}
__device__ __forceinline__ void split2(float a, float b, unsigned int& hi,
                                       unsigned int& lo) {
    unsigned int h0 = f32_to_bf16_rne(a), h1 = f32_to_bf16_rne(b);
    unsigned int l0 = f32_to_bf16_rne(a - bf16_to_f32(h0));
    unsigned int l1 = f32_to_bf16_rne(b - bf16_to_f32(h1));
    hi = h0 | (h1 << 16);
    lo = l0 | (l1 << 16);
}

__device__ __forceinline__ void gl2lds16(const void* g, void* l) {
    __builtin_amdgcn_global_load_lds((__attribute__((address_space(1))) void*)g,
                                     (__attribute__((address_space(3))) void*)l,
                                     16, 0, 0);
}

// ---------------- front: convA + convB + deg (fused, independent) ----------

__global__ void k_front(const float* __restrict__ x, unsigned short* __restrict__ xH,
                        unsigned short* __restrict__ xL,
                        const float* __restrict__ W0, const float* __restrict__ Wh,
                        const float* __restrict__ Rh, unsigned short* __restrict__ bH,
                        unsigned short* __restrict__ bL,
                        const int* __restrict__ ei, int* __restrict__ deg,
                        int* __restrict__ eslot) {
    const int b = blockIdx.x;
    const int tid = threadIdx.x;
    if (b < FRONT_A) {
        // convA: x (f32 row-major) -> swizzled bf16 hi/lo A-fragments.
        int u = b * 256 + tid;
        int lane = u & 63;
        int blk = u >> 6;
        int kblk = blk & 3;
        int rowBlock = blk >> 2;
        int m = rowBlock * 16 + (lane & 15);
        int k = kblk * 32 + (lane >> 4) * 8;
        const float4* p = (const float4*)&x[(size_t)m * 128 + k];
        float4 v0 = p[0];
        float4 v1 = p[1];
        float vals[8] = {v0.x, v0.y, v0.z, v0.w, v1.x, v1.y, v1.z, v1.w};
        union { unsigned int i[4]; uint4 v; } H, L;
#pragma unroll
        for (int j = 0; j < 4; ++j) split2(vals[2 * j], vals[2 * j + 1], H.i[j], L.i[j]);
        *(uint4*)&xH[(size_t)u * 8] = H.v;
        *(uint4*)&xL[(size_t)u * 8] = L.v;
    } else if (b < FRONT_A + FRONT_B) {
        // convB: W [k][n] f32 -> swizzled fragments; 7 matrices.
        int cb = b - FRONT_A;
        int mat = cb >> 3;
        const float* src = (mat == 0) ? W0
                         : (mat <= 3) ? (Wh + (size_t)(mat - 1) * 16384)
                                      : (Rh + (size_t)(mat - 4) * 16384);
        int u = (cb & 7) * 256 + tid;  // 0..2047
        int lane = u & 63;
        int blk = u >> 6;
        int kblk = blk & 3;
        int nb = blk >> 2;
        int n = nb * 16 + (lane & 15);
        int k = kblk * 32 + (lane >> 4) * 8;
        union { unsigned int i[4]; uint4 v; } H, L;
#pragma unroll
        for (int j = 0; j < 4; ++j) {
            float a = src[(size_t)(k + 2 * j) * 128 + n];
            float c = src[(size_t)(k + 2 * j + 1) * 128 + n];
            split2(a, c, H.i[j], L.i[j]);
        }
        size_t base = (size_t)mat * 16384 + (size_t)u * 8;
        *(uint4*)&bH[base] = H.v;
        *(uint4*)&bL[base] = L.v;
    } else {
        // deg + per-edge slot record (removes fill's atomic pass)
        int e = (b - FRONT_A - FRONT_B) * 256 + tid;  // < 800000 exact
        int d = ei[NE + e];
        eslot[e] = atomicAdd(&deg[d], 1);
    }
}

// ---------------- scan1: per-block sums of padded degree + dinv ------------

__global__ void k_scan1(const int* __restrict__ deg, float* __restrict__ dinv,
                        int* __restrict__ bsum) {
    __shared__ int s[256];
    int i = blockIdx.x * 256 + threadIdx.x;
    int d = (i < NN) ? deg[i] : 0;
    if (i < NN) dinv[i] = rsqrtf((float)(d + 1));  // +1 self-loop
    s[threadIdx.x] = (d + 3) & ~3;
    __syncthreads();
    for (int o = 128; o > 0; o >>= 1) {
        if (threadIdx.x < o) s[threadIdx.x] += s[threadIdx.x + o];
        __syncthreads();
    }
    if (threadIdx.x == 0) bsum[blockIdx.x] = s[0];
}

// ---------------- scan3: rowptr (inlines scan2) + CSR pad zeroing ----------

__global__ void k_scan3(const int* __restrict__ deg, const int* __restrict__ bsum,
                        int* __restrict__ rowptr, int* __restrict__ col,
                        float* __restrict__ cfv) {
    __shared__ int s[256];
    __shared__ int offS;
    const int bid = blockIdx.x;
    s[threadIdx.x] = (threadIdx.x < bid) ? bsum[threadIdx.x] : 0;
    __syncthreads();
    for (int o = 128; o > 0; o >>= 1) {
        if (threadIdx.x < o) s[threadIdx.x] += s[threadIdx.x + o];
        __syncthreads();
    }
    if (threadIdx.x == 0) offS = s[0];
    __syncthreads();
    const int off = offS;
    __syncthreads();
    int i = bid * 256 + threadIdx.x;
    int d = (i < NN) ? deg[i] : 0;
    int v = (d + 3) & ~3;
    s[threadIdx.x] = v;
    __syncthreads();
    for (int o = 1; o < 256; o <<= 1) {
        int tv = (threadIdx.x >= o) ? s[threadIdx.x - o] : 0;
        __syncthreads();
        s[threadIdx.x] += tv;
        __syncthreads();
    }
    if (i < NN) {
        int rp = off + s[threadIdx.x] - v;  // exclusive
        rowptr[i] = rp;
        // zero the pad slots (<=3 per row) -> no big memsets needed
        for (int p = rp + d; p < rp + v; ++p) { col[p] = 0; cfv[p] = 0.f; }
    }
}

// ---------------- MFMA GEMM: C1 = A @ B1 [, C2 = A @ B2], split-bf16 --------
// R7-proven inline body (shared decl + staging in the SAME kernel scope — the
// R8 device-function/generic-LDS-pointer form ICE'd clang). FILL=true adds
// CSR-fill blocks past GEMM_GRID (block-uniform early return, no barrier).
// 64x128 tile, 4 waves 2x2, wave tile 32x64 = 2x4 mfma 16x16x32 tiles.

template <int NB, bool FILL>
__global__ __launch_bounds__(256, 3) void k_gemm_mfma(
    const unsigned short* __restrict__ Ahi, const unsigned short* __restrict__ Alo,
    const unsigned short* __restrict__ B1hi, const unsigned short* __restrict__ B1lo,
    const unsigned short* __restrict__ B2hi, const unsigned short* __restrict__ B2lo,
    float* __restrict__ C1, float* __restrict__ C2,
    const int* __restrict__ ei, const int* __restrict__ rowptr,
    const int* __restrict__ eslot, const float* __restrict__ dinv,
    int* __restrict__ col, float* __restrict__ cfv) {
    __shared__ unsigned short lds[(1 + 2 * NB) * 4096];
    if (FILL && blockIdx.x >= GEMM_GRID) {
        int e = (blockIdx.x - GEMM_GRID) * 256 + threadIdx.x;  // < 800000 exact
        int s = ei[e];
        int d = ei[NE + e];
        int p = rowptr[d] + eslot[e];
        col[p] = s;
        cfv[p] = dinv[s];
        return;
    }
    unsigned short* AhiS = lds;             // 2048
    unsigned short* AloS = lds + 2048;      // 2048
    unsigned short* B1hiS = lds + 4096;     // 4096
    unsigned short* B1loS = lds + 8192;     // 4096
    unsigned short* B2hiS = lds + 12288;    // NB==2 only
    unsigned short* B2loS = lds + 16384;

    const int tid = threadIdx.x;
    const int wave = tid >> 6;
    const int lane = tid & 63;
    const int wm = wave & 1;
    const int wn = wave >> 1;
    const int rb0 = blockIdx.x * 4;         // first 16-row block

    floatx4 acc1[2][4], acc2[2][4];
    floatx4 zero = {0.f, 0.f, 0.f, 0.f};
#pragma unroll
    for (int i = 0; i < 2; ++i)
#pragma unroll
        for (int j = 0; j < 4; ++j) { acc1[i][j] = zero; if (NB == 2) acc2[i][j] = zero; }

    for (int kc = 0; kc < 4; ++kc) {
        const int nit = (NB == 2) ? 10 : 6;  // units: A 8 + B 16*NB, / 4 waves
#pragma unroll
        for (int it = 0; it < nit; ++it) {
            int i = it * 4 + wave;
            const unsigned short* src;
            unsigned short* dst;
            if (i < 4)       { src = Ahi  + ((size_t)(rb0 + i) * 4 + kc) * 512;       dst = AhiS  + i * 512; }
            else if (i < 8)  { int rb = i - 4;  src = Alo  + ((size_t)(rb0 + rb) * 4 + kc) * 512; dst = AloS  + rb * 512; }
            else if (i < 16) { int nb = i - 8;  src = B1hi + ((size_t)nb * 4 + kc) * 512;         dst = B1hiS + nb * 512; }
            else if (i < 24) { int nb = i - 16; src = B1lo + ((size_t)nb * 4 + kc) * 512;         dst = B1loS + nb * 512; }
            else if (i < 32) { int nb = i - 24; src = B2hi + ((size_t)nb * 4 + kc) * 512;         dst = B2hiS + nb * 512; }
            else             { int nb = i - 32; src = B2lo + ((size_t)nb * 4 + kc) * 512;         dst = B2loS + nb * 512; }
            gl2lds16(src + (size_t)lane * 8, dst);
        }
        __syncthreads();

        bf16x8 aH[2], aL[2], bH[4], bL[4];
#pragma unroll
        for (int t = 0; t < 2; ++t)
            aH[t] = *(const bf16x8*)(AhiS + (wm * 2 + t) * 512 + lane * 8);
#pragma unroll
        for (int t = 0; t < 4; ++t)
            bH[t] = *(const bf16x8*)(B1hiS + (wn * 4 + t) * 512 + lane * 8);
#pragma unroll
        for (int tm = 0; tm < 2; ++tm)
#pragma unroll
            for (int tn = 0; tn < 4; ++tn)
                acc1[tm][tn] = __builtin_amdgcn_mfma_f32_16x16x32_bf16(
                    aH[tm], bH[tn], acc1[tm][tn], 0, 0, 0);
#pragma unroll
        for (int t = 0; t < 4; ++t)
            bL[t] = *(const bf16x8*)(B1loS + (wn * 4 + t) * 512 + lane * 8);
#pragma unroll
        for (int tm = 0; tm < 2; ++tm)
#pragma unroll
            for (int tn = 0; tn < 4; ++tn)
                acc1[tm][tn] = __builtin_amdgcn_mfma_f32_16x16x32_bf16(
                    aH[tm], bL[tn], acc1[tm][tn], 0, 0, 0);
#pragma unroll
        for (int t = 0; t < 2; ++t)
            aL[t] = *(const bf16x8*)(AloS + (wm * 2 + t) * 512 + lane * 8);
#pragma unroll
        for (int tm = 0; tm < 2; ++tm)
#pragma unroll
            for (int tn = 0; tn < 4; ++tn)
                acc1[tm][tn] = __builtin_amdgcn_mfma_f32_16x16x32_bf16(
                    aL[tm], bH[tn], acc1[tm][tn], 0, 0, 0);
        if (NB == 2) {
#pragma unroll
            for (int t = 0; t < 4; ++t)
                bH[t] = *(const bf16x8*)(B2hiS + (wn * 4 + t) * 512 + lane * 8);
#pragma unroll
            for (int tm = 0; tm < 2; ++tm)
#pragma unroll
                for (int tn = 0; tn < 4; ++tn)
                    acc2[tm][tn] = __builtin_amdgcn_mfma_f32_16x16x32_bf16(
                        aH[tm], bH[tn], acc2[tm][tn], 0, 0, 0);
#pragma unroll
            for (int tm = 0; tm < 2; ++tm)
#pragma unroll
                for (int tn = 0; tn < 4; ++tn)
                    acc2[tm][tn] = __builtin_amdgcn_mfma_f32_16x16x32_bf16(
                        aL[tm], bH[tn], acc2[tm][tn], 0, 0, 0);
#pragma unroll
            for (int t = 0; t < 4; ++t)
                bL[t] = *(const bf16x8*)(B2loS + (wn * 4 + t) * 512 + lane * 8);
#pragma unroll
            for (int tm = 0; tm < 2; ++tm)
#pragma unroll
                for (int tn = 0; tn < 4; ++tn)
                    acc2[tm][tn] = __builtin_amdgcn_mfma_f32_16x16x32_bf16(
                        aH[tm], bL[tn], acc2[tm][tn], 0, 0, 0);
        }
        __syncthreads();
    }

    // epilogue: C/D layout col = lane&15, row = (lane>>4)*4 + r
    const int quad = lane >> 4;
    const int col0 = lane & 15;
    const int rowBase = blockIdx.x * 64 + wm * 32;
#pragma unroll
    for (int tm = 0; tm < 2; ++tm) {
#pragma unroll
        for (int tn = 0; tn < 4; ++tn) {
            int c = wn * 64 + tn * 16 + col0;
#pragma unroll
            for (int r = 0; r < 4; ++r) {
                int row = rowBase + tm * 16 + quad * 4 + r;
                if (row < NN) {
                    C1[(size_t)row * 128 + c] = acc1[tm][tn][r];
                    if (NB == 2) C2[(size_t)row * 128 + c] = acc2[tm][tn][r];
                }
            }
        }
    }
}

// ---------------- SpMM + epilogue ------------------------------------------
// Block = 16 nodes: 4 waves x 4 serial nodes; 1 node/wave gather, lane ->
// features (2l,2l+1), one 512 B contiguous row per gather instr.
// non-LAST: LDS-staged swizzled bf16 hi/lo output (next GEMM's A operand).
// LAST: no h output — fused global-max-pool via per-graph running max
// (nodes are batch-sorted) + atomicMax into pooled.

template <bool RES, bool LAST>
__global__ __launch_bounds__(256) void k_spmm(const float* __restrict__ t,
                                              const float* __restrict__ r,
                                              const int* __restrict__ rowptr,
                                              const int* __restrict__ deg,
                                              const int* __restrict__ col,
                                              const float* __restrict__ cfv,
                                              const float* __restrict__ dinv,
                                              const float* __restrict__ bias,
                                              const float* __restrict__ gamma,
                                              const float* __restrict__ beta,
                                              unsigned short* __restrict__ hHi,
                                              unsigned short* __restrict__ hLo,
                                              const int* __restrict__ batch,
                                              float* __restrict__ pooled) {
    __shared__ unsigned short shH[16][136];  // +8 shorts pad
    __shared__ unsigned short shL[16][136];
    const int lane = threadIdx.x & 63;
    const int wave = threadIdx.x >> 6;
    const int f = lane * 2;
    const float2 bv = *(const float2*)&bias[f];
    const float2 gv = *(const float2*)&gamma[f];
    const float2 ev = *(const float2*)&beta[f];

    int curg = -1;
    float mx = 0.f, my = 0.f;

#pragma unroll 1
    for (int i = 0; i < 4; ++i) {
        const int nl = wave * 4 + i;
        const int node = blockIdx.x * 16 + nl;   // grid = NN/16 exact
        const int start = rowptr[node];          // multiple of 4, 16B-aligned
        const int cnt4 = (deg[node] + 3) >> 2;
        float ax = 0.f, ay = 0.f;
#pragma unroll 2
        for (int q = 0; q < cnt4; ++q) {
            int4 cs = *(const int4*)&col[start + q * 4];
            float4 wv = *(const float4*)&cfv[start + q * 4];
            float2 v0 = *(const float2*)&t[(size_t)cs.x * 128 + f];
            float2 v1 = *(const float2*)&t[(size_t)cs.y * 128 + f];
            float2 v2 = *(const float2*)&t[(size_t)cs.z * 128 + f];
            float2 v3 = *(const float2*)&t[(size_t)cs.w * 128 + f];
            ax = fmaf(wv.x, v0.x, ax); ay = fmaf(wv.x, v0.y, ay);
            ax = fmaf(wv.y, v1.x, ax); ay = fmaf(wv.y, v1.y, ay);
            ax = fmaf(wv.z, v2.x, ax); ay = fmaf(wv.z, v2.y, ay);
            ax = fmaf(wv.w, v3.x, ax); ay = fmaf(wv.w, v3.y, ay);
        }
        const float di = dinv[node];
        const float dii = di * di;
        float2 tv = *(const float2*)&t[(size_t)node * 128 + f];
        float cx = di * ax + dii * tv.x + bv.x;
        float cy = di * ay + dii * tv.y + bv.y;
        if (RES) {
            float2 rv = *(const float2*)&r[(size_t)node * 128 + f];
            cx += rv.x;
            cy += rv.y;
        }
        float ox = fmaxf(cx * (BN_INV * gv.x) + ev.x, 0.f);
        float oy = fmaxf(cy * (BN_INV * gv.y) + ev.y, 0.f);
        if (LAST) {
            int g = batch[node];  // non-decreasing over the wave's node sequence
            if (g != curg) {
                if (curg >= 0) {
                    atomicMax((unsigned int*)&pooled[curg * 128 + f], __float_as_uint(mx));
                    atomicMax((unsigned int*)&pooled[curg * 128 + f + 1], __float_as_uint(my));
                }
                curg = g; mx = ox; my = oy;
            } else {
                mx = fmaxf(mx, ox);
                my = fmaxf(my, oy);
            }
        } else {
            unsigned int H, L;
            split2(ox, oy, H, L);
            ((unsigned int*)&shH[nl][0])[lane] = H;
            ((unsigned int*)&shL[nl][0])[lane] = L;
        }
    }

    if (LAST) {
        if (curg >= 0) {
            atomicMax((unsigned int*)&pooled[curg * 128 + f], __float_as_uint(mx));
            atomicMax((unsigned int*)&pooled[curg * 128 + f + 1], __float_as_uint(my));
        }
        return;
    }
    __syncthreads();

    // emit 4 hi + 4 lo units (1 KB each), fully coalesced
    const int u = threadIdx.x >> 6;   // kblk
    const int l = threadIdx.x & 63;
    const int m = l & 15;
    const int kg = l >> 4;
    uint4 H4 = *(const uint4*)&shH[m][u * 32 + kg * 8];
    uint4 L4 = *(const uint4*)&shL[m][u * 32 + kg * 8];
    ((uint4*)hHi)[((size_t)blockIdx.x * 4 + u) * 64 + l] = H4;
    ((uint4*)hLo)[((size_t)blockIdx.x * 4 + u) * 64 + l] = L4;
}

// ---------------- MLP head ----------------

__global__ void k_head(const float* __restrict__ pooled, const float* __restrict__ mW1,
                       const float* __restrict__ mb1, const float* __restrict__ mW2,
                       const float* __restrict__ mb2, float* __restrict__ out) {
    __shared__ float p[128];
    __shared__ float z[128];
    int g = blockIdx.x;
    int j = threadIdx.x;  // 128 threads
    p[j] = pooled[g * 128 + j];
    __syncthreads();
    float a = mb1[j];
#pragma unroll 8
    for (int k = 0; k < 128; ++k) a += p[k] * mW1[k * 128 + j];
    z[j] = fmaxf(a, 0.f);
    __syncthreads();
    if (j < NCLASS) {
        float o = mb2[j];
#pragma unroll 8
        for (int k = 0; k < 128; ++k) o += z[k] * mW2[k * NCLASS + j];
        out[g * NCLASS + j] = o;
    }
}

// ---------------- launcher ----------------

extern "C" void kernel_launch(void* const* d_in, const int* in_sizes, int n_in,
                              void* d_out, int out_size, void* d_ws, size_t ws_size,
                              hipStream_t stream) {
    const float* x   = (const float*)d_in[0];
    const int*   ei  = (const int*)d_in[1];
    const int* batch = (const int*)d_in[2];
    const float* W0  = (const float*)d_in[3];
    const float* b0  = (const float*)d_in[4];
    const float* g0  = (const float*)d_in[5];
    const float* be0 = (const float*)d_in[6];
    const float* Wh  = (const float*)d_in[7];
    const float* bh  = (const float*)d_in[8];
    const float* gh  = (const float*)d_in[9];
    const float* beh = (const float*)d_in[10];
    const float* Rh  = (const float*)d_in[11];
    const float* mW1 = (const float*)d_in[12];
    const float* mb1 = (const float*)d_in[13];
    const float* mW2 = (const float*)d_in[14];
    const float* mb2 = (const float*)d_in[15];
    float* out = (float*)d_out;

    char* ws = (char*)d_ws;
    size_t off = 0;
    auto alloc = [&](size_t bytes) -> void* {
        void* p = ws + off;
        off += (bytes + 255) & ~(size_t)255;
        return p;
    };
    // deg + pooled adjacent -> single memset covers both
    int*   deg    = (int*)alloc((size_t)NN * 4);
    float* pooled = (float*)alloc((size_t)NGRAPH * HID * 4);
    size_t zspan = (size_t)((char*)pooled - (char*)deg) + (size_t)NGRAPH * HID * 4;
    int*   rowptr = (int*)alloc((size_t)NN * 4);
    float* dinv   = (float*)alloc((size_t)NN * 4);
    int*   bsum   = (int*)alloc(256 * 4);
    int*   eslot  = (int*)alloc((size_t)NE * 4);
    int*   col    = (int*)alloc((size_t)NEPAD * 4);
    float* cfv    = (float*)alloc((size_t)NEPAD * 4);
    float* t      = (float*)alloc((size_t)NN * HID * 4);
    float* rbuf   = (float*)alloc((size_t)NN * HID * 4);
    // swizzled bf16 hi/lo activations: x + 2 ping-pong sets
    const size_t ASZ = (size_t)ROWBLK_PAD * 4 * 512;  // elements
    unsigned short* xH = (unsigned short*)alloc(ASZ * 2);
    unsigned short* xL = (unsigned short*)alloc(ASZ * 2);
    unsigned short* hH0 = (unsigned short*)alloc(ASZ * 2);
    unsigned short* hL0 = (unsigned short*)alloc(ASZ * 2);
    unsigned short* hH1 = (unsigned short*)alloc(ASZ * 2);
    unsigned short* hL1 = (unsigned short*)alloc(ASZ * 2);
    // swizzled weights, 7 matrices
    unsigned short* bH = (unsigned short*)alloc((size_t)7 * 16384 * 2);
    unsigned short* bL = (unsigned short*)alloc((size_t)7 * 16384 * 2);

    hipMemsetAsync(deg, 0, zspan, stream);

    k_front<<<FRONT_GRID, 256, 0, stream>>>(x, xH, xL, W0, Wh, Rh, bH, bL,
                                            ei, deg, eslot);
    k_scan1<<<(NN + 255) / 256, 256, 0, stream>>>(deg, dinv, bsum);
    k_scan3<<<(NN + 255) / 256, 256, 0, stream>>>(deg, bsum, rowptr, col, cfv);

    // GEMM0 fused with CSR fill (independent work in one dispatch)
    k_gemm_mfma<1, true><<<GEMM_GRID + FILL_GRID, 256, 0, stream>>>(
        xH, xL, bH, bL, nullptr, nullptr, t, nullptr,
        ei, rowptr, eslot, dinv, col, cfv);

    const int spmmGrid = NN / 16;  // 3125
    k_spmm<false, false><<<spmmGrid, 256, 0, stream>>>(
        t, nullptr, rowptr, deg, col, cfv, dinv, b0, g0, be0, hH0, hL0,
        nullptr, nullptr);

    unsigned short* hh[2] = {hH0, hH1};
    unsigned short* hl[2] = {hL0, hL1};
    int cur = 0;
    for (int i = 0; i < LHID; ++i) {
        unsigned short* ih = hh[cur];
        unsigned short* il = hl[cur];
        unsigned short* oh = hh[cur ^ 1];
        unsigned short* ol = hl[cur ^ 1];
        const unsigned short* w1H = bH + (size_t)(1 + i) * 16384;
        const unsigned short* w1L = bL + (size_t)(1 + i) * 16384;
        const unsigned short* w2H = bH + (size_t)(4 + i) * 16384;
        const unsigned short* w2L = bL + (size_t)(4 + i) * 16384;
        k_gemm_mfma<2, false><<<GEMM_GRID, 256, 0, stream>>>(
            ih, il, w1H, w1L, w2H, w2L, t, rbuf,
            nullptr, nullptr, nullptr, nullptr, nullptr, nullptr);
        if (i < LHID - 1)
            k_spmm<true, false><<<spmmGrid, 256, 0, stream>>>(
                t, rbuf, rowptr, deg, col, cfv, dinv, bh + i * HID, gh + i * HID,
                beh + i * HID, oh, ol, nullptr, nullptr);
        else
            k_spmm<true, true><<<spmmGrid, 256, 0, stream>>>(
                t, rbuf, rowptr, deg, col, cfv, dinv, bh + i * HID, gh + i * HID,
                beh + i * HID, nullptr, nullptr, batch, pooled);
        cur ^= 1;
    }

    k_head<<<NGRAPH, 128, 0, stream>>>(pooled, mW1, mb1, mW2, mb2, out);
}